// Round 14
// baseline (401.384 us; speedup 1.0000x reference)
//
#include <hip/hip_runtime.h>
#include <stdint.h>

// ---------- types & helpers ----------
typedef __attribute__((ext_vector_type(8))) short v8s;   // 8 x bf16 (4 VGPRs)
typedef __attribute__((ext_vector_type(4))) float v4f;   // MFMA C/D frag

__device__ __forceinline__ uint16_t f2bf(float x){
  uint32_t u = __float_as_uint(x);
  return (uint16_t)((u + 0x7FFFu + ((u >> 16) & 1u)) >> 16);  // RNE
}
__device__ __forceinline__ uint32_t pk2(float a, float b){
  return (uint32_t)f2bf(a) | ((uint32_t)f2bf(b) << 16);
}

// async global->LDS, 16B per lane. LDS dest is wave-uniform-base + lane*16 (linear).
__device__ __forceinline__ void gl16(const uint16_t* g, uint16_t* l){
  __builtin_amdgcn_global_load_lds((const __attribute__((address_space(1))) void*)g,
                                   (__attribute__((address_space(3))) void*)l, 16, 0, 0);
}

// ---------- fused prep: one launch, block-range dispatch over 10 independent jobs ----------
// [0,12544)      tdec    : dec f32 NCHW -> decT bf16 [b][pos][ci]  (block-rotation swizzle)
// [12544,20736)  wpe2    : pe_w -> [co][pix*512+ci] bf16
// [20736,20864)  cvt mcw ; [20864,20992) cvt rcw
// [20992,21120)  tcvt wq ; [21120,21312) tcvt wk ; [21312,21504) tcvt wv ; [21504,21632) tcvt wo
// [21632,22304)  transb  ; [22304,22306) scales
__device__ __forceinline__ void prep_cvt(const float* s, uint16_t* d, int id, int n8){
  if (id >= n8) return;
  const float4* sp = (const float4*)(s + (size_t)id * 8);
  float4 f0 = sp[0], f1 = sp[1];
  uint4 u; u.x = pk2(f0.x, f0.y); u.y = pk2(f0.z, f0.w);
  u.z = pk2(f1.x, f1.y); u.w = pk2(f1.z, f1.w);
  *(uint4*)(d + (size_t)id * 8) = u;
}
__device__ __forceinline__ void prep_tcvt(const float* s, uint16_t* d, int id, int R, int C){
  int r8 = R >> 3;
  if (id >= C * r8) return;
  int c = id / r8, r0 = (id - c * r8) * 8;
  float v[8];
  #pragma unroll
  for (int e = 0; e < 8; e++) v[e] = s[(size_t)(r0 + e) * C + c];
  uint4 u; u.x = pk2(v[0], v[1]); u.y = pk2(v[2], v[3]);
  u.z = pk2(v[4], v[5]); u.w = pk2(v[6], v[7]);
  *(uint4*)(d + (size_t)c * R + r0) = u;
}

__global__ void __launch_bounds__(256) dra_prep(
    const float* __restrict__ dec, uint16_t* __restrict__ decT,
    const float* __restrict__ pw, uint16_t* __restrict__ w2,
    const float* __restrict__ mc_w, uint16_t* __restrict__ mcw,
    const float* __restrict__ rc_w, uint16_t* __restrict__ rcw,
    const float* __restrict__ wq, uint16_t* __restrict__ wqT,
    const float* __restrict__ wk, uint16_t* __restrict__ wkT,
    const float* __restrict__ wv, uint16_t* __restrict__ wvT,
    const float* __restrict__ wo, uint16_t* __restrict__ woT,
    const float* __restrict__ tr, uint16_t* __restrict__ transb,
    const float* __restrict__ mcb, const float* __restrict__ g1, const float* __restrict__ b1,
    const float* __restrict__ m1, const float* __restrict__ v1,
    const float* __restrict__ rcb, const float* __restrict__ g2, const float* __restrict__ b2,
    const float* __restrict__ m2, const float* __restrict__ v2,
    float* __restrict__ s1, float* __restrict__ o1, float* __restrict__ s2, float* __restrict__ o2)
{
  __shared__ uint16_t lt[64 * 64];   // [pos][ci], block-rotation swizzle, stride 64
  int B = blockIdx.x, t = threadIdx.x;

  if (B < 12544){                                   // ---- tdec ----
    int pos0 = (B % 196) * 64;
    int ci0  = ((B / 196) & 7) * 64;
    int b    = B / 1568;
    // write: element (p,c) -> lt[p*64 + (((c>>3)+(p>>2))&7)*8 + (c&7)]
    // banks: 4*((C+q)&7) + (c&7)>>1, q=p>>2 spans 0..15 -> 16 banks, 4-way (vs 32-way before)
    #pragma unroll
    for (int i = 0; i < 4; i++){
      int idx = t + i * 256;
      int ci_l = idx >> 4, p4 = (idx & 15) * 4;
      const float4 f = *(const float4*)(dec + ((size_t)(b * 512 + ci0 + ci_l)) * 12544 + pos0 + p4);
      float v[4] = {f.x, f.y, f.z, f.w};
      #pragma unroll
      for (int j = 0; j < 4; j++){
        int p = p4 + j;
        int bp = ((ci_l >> 3) + (p >> 2)) & 7;
        lt[p * 64 + bp * 8 + (ci_l & 7)] = f2bf(v[j]);
      }
    }
    __syncthreads();
    // read: logical block u of row p_l sits at physical block (u + (p_l>>2))&7;
    // within-block order preserved -> uint4 is layout-correct. Banks 4*bp: conflict-free.
    #pragma unroll
    for (int i = 0; i < 2; i++){
      int idx = t + i * 256;
      int p_l = idx >> 3, u = idx & 7;
      int bp = (u + (p_l >> 2)) & 7;
      uint4 v = *(const uint4*)&lt[p_l * 64 + bp * 8];
      *(uint4*)(decT + ((size_t)b * 12544 + pos0 + p_l) * 512 + ci0 + u * 8) = v;
    }
  } else if (B < 20736){                            // ---- wpe2 ----
    int id = (B - 12544) * 256 + t;
    if (id < 2097152){
      int co = id >> 12, rem = id & 4095;
      int ci8 = rem >> 6, pix = rem & 63;
      const float* s = pw + (size_t)co * 32768 + ci8 * 512 + pix;
      float v[8];
      #pragma unroll
      for (int j = 0; j < 8; j++) v[j] = s[j * 64];
      uint4 u; u.x = pk2(v[0], v[1]); u.y = pk2(v[2], v[3]);
      u.z = pk2(v[4], v[5]); u.w = pk2(v[6], v[7]);
      *(uint4*)(w2 + (size_t)co * 32768 + pix * 512 + ci8 * 8) = u;
    }
  } else if (B < 20864){ prep_cvt(mc_w, mcw, (B - 20736) * 256 + t, 32768); }
  else if (B < 20992){ prep_cvt(rc_w, rcw, (B - 20864) * 256 + t, 32768); }
  else if (B < 21120){ prep_tcvt(wq, wqT, (B - 20992) * 256 + t, 512, 512); }
  else if (B < 21312){ prep_tcvt(wk, wkT, (B - 21120) * 256 + t, 768, 512); }
  else if (B < 21504){ prep_tcvt(wv, wvT, (B - 21312) * 256 + t, 768, 512); }
  else if (B < 21632){ prep_tcvt(wo, woT, (B - 21504) * 256 + t, 512, 512); }
  else if (B < 22304){                              // ---- transb ----
    int id = (B - 21632) * 256 + t;
    if (id < 1792 * 96){
      int n = id / 96, e0 = (id - n * 96) * 8;
      int b = n / 224, nl = n - b * 224;
      uint4 u = {0u,0u,0u,0u};
      if (nl < 196){
        const float* sp = tr + ((size_t)(b * 196 + nl)) * 768 + e0;
        u.x = pk2(sp[0], sp[1]); u.y = pk2(sp[2], sp[3]);
        u.z = pk2(sp[4], sp[5]); u.w = pk2(sp[6], sp[7]);
      }
      *(uint4*)(transb + (size_t)n * 768 + e0) = u;
    }
  } else {                                          // ---- scales ----
    int i = (B - 22304) * 256 + t;
    if (i < 512){
      float sc1 = g1[i] / sqrtf(v1[i] + 1e-3f);
      s1[i] = sc1; o1[i] = (mcb[i] - m1[i]) * sc1 + b1[i];
      float sc2 = g2[i] / sqrtf(v2[i] + 1e-3f);
      s2[i] = sc2; o2[i] = (rcb[i] - m2[i]) * sc2 + b2[i];
    }
  }
}

// ---------- K1: patch-embed as split-K GEMM with partial buffers (round-5 best) ----------
__global__ void __launch_bounds__(256, 4) dra_k1(const uint16_t* __restrict__ decT,
    const uint16_t* __restrict__ wpe2, float* __restrict__ part)
{
  __shared__ uint16_t lA[128 * 32];
  __shared__ uint16_t lB[128 * 32];
  int t = threadIdx.x;
  int L = blockIdx.x;
  int x = L & 7, n = L >> 3;           // n in [0,112)
  int shi = n / 56, rem = n - shi * 56;
  int tok_t = rem >> 2, co_t = rem & 3;
  int s    = shi * 8 + x;              // split 0..15 pinned to xcd x
  int bco  = co_t * 128;
  int tok0 = tok_t * 128;
  int lane = t & 63, w = t >> 6;
  int wm = w >> 1, wn = w & 1;
  int lr = lane & 15, lg = lane >> 4;

  const uint16_t* aB[2]; const uint16_t* bB[2]; int uu[2];
  #pragma unroll
  for (int i = 0; i < 2; i++){
    int u = t + i * 256; uu[i] = u;
    int row = u >> 2, h = u & 3;
    int token = tok0 + row;
    int b = token / 224, tl = token - b * 224;
    if (tl > 195) tl = 195;                       // clamp pad tokens (finite garbage, unused later)
    int py = tl / 14, px = tl - py * 14;
    aB[i] = decT + ((size_t)b * 12544 + py * 896 + px * 8) * 512 + h * 8;
    bB[i] = wpe2 + (size_t)(bco + row) * 32768 + h * 8;
  }

  const v4f vzero = {0.f,0.f,0.f,0.f};
  v4f acc[4][4];
  #pragma unroll
  for (int i = 0; i < 4; i++)
    #pragma unroll
    for (int j = 0; j < 4; j++) acc[i][j] = vzero;

  for (int pix = s * 4; pix < s * 4 + 4; ++pix){
    int ky = pix >> 3, kx = pix & 7;
    int poff = (ky * 112 + kx) * 512;
    int k0p  = pix * 512;
    for (int ci0 = 0; ci0 < 512; ci0 += 32){
      gl16(aB[0] + poff + ci0, &lA[uu[0] * 8]);
      gl16(aB[1] + poff + ci0, &lA[uu[1] * 8]);
      gl16(bB[0] + k0p + ci0,  &lB[uu[0] * 8]);
      gl16(bB[1] + k0p + ci0,  &lB[uu[1] * 8]);
      __syncthreads();
      v8s av[4], bv[4];
      #pragma unroll
      for (int mf = 0; mf < 4; mf++) av[mf] = *(const v8s*)&lA[(wm*64 + mf*16 + lr) * 32 + lg * 8];
      #pragma unroll
      for (int nf = 0; nf < 4; nf++) bv[nf] = *(const v8s*)&lB[(wn*64 + nf*16 + lr) * 32 + lg * 8];
      #pragma unroll
      for (int mf = 0; mf < 4; mf++)
        #pragma unroll
        for (int nf = 0; nf < 4; nf++)
          acc[mf][nf] = __builtin_amdgcn_mfma_f32_16x16x32_bf16(av[mf], bv[nf], acc[mf][nf], 0, 0, 0);
      __syncthreads();
    }
  }
  float* pd = part + (size_t)s * 917504;
  #pragma unroll
  for (int mf = 0; mf < 4; mf++){
    #pragma unroll
    for (int nf = 0; nf < 4; nf++){
      int tokg = tok0 + wm*64 + mf*16 + lg*4;
      int cog  = bco  + wn*64 + nf*16 + lr;
      #pragma unroll
      for (int r = 0; r < 4; r++)
        pd[(size_t)(tokg + r) * 512 + cog] = acc[mf][nf][r];
    }
  }
}

// reduce 16 split partials + bias -> dlb bf16 [1792][512]
__global__ void __launch_bounds__(256) dra_red(const float* __restrict__ part,
    const float* __restrict__ peb, uint16_t* __restrict__ dlb){
  int id = blockIdx.x * 256 + threadIdx.x;
  if (id >= 114688) return;
  int tok = id >> 6, c8 = (id & 63) * 8;
  float a0=0,a1=0,a2=0,a3=0,a4=0,a5=0,a6=0,a7=0;
  #pragma unroll
  for (int s = 0; s < 16; s++){
    const float* p = part + (size_t)s * 917504 + (size_t)tok * 512 + c8;
    float4 x = *(const float4*)p, y = *(const float4*)(p + 4);
    a0 += x.x; a1 += x.y; a2 += x.z; a3 += x.w;
    a4 += y.x; a5 += y.y; a6 += y.z; a7 += y.w;
  }
  const float4 b0 = *(const float4*)(peb + c8), b1 = *(const float4*)(peb + c8 + 4);
  uint4 o; o.x = pk2(a0 + b0.x, a1 + b0.y); o.y = pk2(a2 + b0.z, a3 + b0.w);
  o.z = pk2(a4 + b1.x, a5 + b1.y); o.w = pk2(a6 + b1.z, a7 + b1.w);
  *(uint4*)(dlb + (size_t)tok * 512 + c8) = o;
}

// ---------- generic NT GEMM (attention chain): D[m][n] = sum_k A[m][k]*B[n][k] ----------
// BM = MREP*32, BN=64, BK=32, 256 threads (2x2 waves). Staging via global_load_lds with
// source-chunk swizzle c^((row>>1)&3): even rows cycle all 4 slots -> 2 lanes/bank (free).
template<int MREP>
__global__ void __launch_bounds__(256, 2) dra_gemm(
    const uint16_t* __restrict__ A, const uint16_t* __restrict__ Bn, void* __restrict__ Dv,
    int M, int N, int K, int lda, int ldb, int ldd,
    long long sAz, long long sBz, long long sDz,
    int epi, const float* __restrict__ svec, const float* __restrict__ ovec)
{
  constexpr int BM = MREP * 32;
  __shared__ uint16_t lA[BM * 32];
  __shared__ uint16_t lB[64 * 32];
  int t = threadIdx.x, z = blockIdx.z;
  int bm = blockIdx.x * BM, bn = blockIdx.y * 64;
  const uint16_t* Az = A + (size_t)z * sAz;
  const uint16_t* Bz = Bn + (size_t)z * sBz;
  int lane = t & 63, w = t >> 6;
  int wm = w >> 1, wn = w & 1;
  int lr = lane & 15, lg = lane >> 4;

  const uint16_t* aSrc[MREP/2]; int uuA[MREP/2];
  #pragma unroll
  for (int i = 0; i < MREP/2; i++){
    int u = t + i * 256; uuA[i] = u;
    int row = u >> 2, c = u & 3;
    int cs = c ^ ((row >> 1) & 3);
    int rg = bm + row; if (rg >= M) rg = M - 1;
    aSrc[i] = Az + (size_t)rg * lda + cs * 8;
  }
  const uint16_t* bSrc;
  {
    int row = t >> 2, c = t & 3;
    int cs = c ^ ((row >> 1) & 3);
    bSrc = Bz + (size_t)(bn + row) * ldb + cs * 8;
  }

  int aoff[MREP], boff[2];
  #pragma unroll
  for (int mf = 0; mf < MREP; mf++){
    int R = wm*(MREP*16) + mf*16 + lr;
    aoff[mf] = R * 32 + (lg ^ ((R >> 1) & 3)) * 8;
  }
  #pragma unroll
  for (int nf = 0; nf < 2; nf++){
    int R = wn*32 + nf*16 + lr;
    boff[nf] = R * 32 + (lg ^ ((R >> 1) & 3)) * 8;
  }

  const v4f vzero = {0.f, 0.f, 0.f, 0.f};
  v4f acc[MREP][2];
  #pragma unroll
  for (int i = 0; i < MREP; i++){ acc[i][0] = vzero; acc[i][1] = vzero; }

  for (int k0 = 0; k0 < K; k0 += 32){
    #pragma unroll
    for (int i = 0; i < MREP/2; i++)
      gl16(aSrc[i] + k0, &lA[uuA[i] * 8]);
    gl16(bSrc + k0, &lB[t * 8]);
    __syncthreads();
    v8s av[MREP], bv[2];
    #pragma unroll
    for (int mf = 0; mf < MREP; mf++) av[mf] = *(const v8s*)&lA[aoff[mf]];
    #pragma unroll
    for (int nf = 0; nf < 2; nf++)    bv[nf] = *(const v8s*)&lB[boff[nf]];
    #pragma unroll
    for (int mf = 0; mf < MREP; mf++)
      #pragma unroll
      for (int nf = 0; nf < 2; nf++)
        acc[mf][nf] = __builtin_amdgcn_mfma_f32_16x16x32_bf16(av[mf], bv[nf], acc[mf][nf], 0, 0, 0);
    __syncthreads();
  }

  #pragma unroll
  for (int mf = 0; mf < MREP; mf++){
    #pragma unroll
    for (int nf = 0; nf < 2; nf++){
      int mg0 = bm + wm*(MREP*16) + mf*16 + lg*4;
      int ng  = bn + wn*32 + nf*16 + lr;
      #pragma unroll
      for (int r = 0; r < 4; r++){
        int mg = mg0 + r;
        if (mg < M){
          float val = acc[mf][nf][r];
          size_t di = (size_t)z * sDz + (size_t)mg * ldd + ng;
          if (epi == 0)      ((float*)Dv)[di] = val;
          else if (epi == 1) ((uint16_t*)Dv)[di] = f2bf(val);
          else ((float*)Dv)[di] = fmaxf(val * svec[mg] + ovec[mg], 0.f);
        }
      }
    }
  }
}

// ---------- InstanceNorm stats: two-stage deterministic tree reduction ----------
__global__ void __launch_bounds__(256) dra_stats1(const float* __restrict__ sim,
                                                  double* __restrict__ ps){
  __shared__ double d1[256], d2[256];
  int b = blockIdx.y, blk = blockIdx.x, t = threadIdx.x;
  const float* s = sim + (size_t)b * 262144 + (size_t)blk * 2048 + t * 8;
  float4 x = *(const float4*)s, y = *(const float4*)(s + 4);
  double p1 = (double)x.x + x.y + x.z + x.w + y.x + y.y + y.z + y.w;
  double p2 = (double)x.x*x.x + (double)x.y*x.y + (double)x.z*x.z + (double)x.w*x.w
            + (double)y.x*y.x + (double)y.y*y.y + (double)y.z*y.z + (double)y.w*y.w;
  d1[t] = p1; d2[t] = p2;
  __syncthreads();
  for (int o = 128; o > 0; o >>= 1){
    if (t < o){ d1[t] += d1[t + o]; d2[t] += d2[t + o]; }
    __syncthreads();
  }
  if (t == 0){
    ps[(b * 128 + blk) * 2 + 0] = d1[0];
    ps[(b * 128 + blk) * 2 + 1] = d2[0];
  }
}

__global__ void __launch_bounds__(128) dra_stats2(const double* __restrict__ ps,
    const float* __restrict__ psig, const float* __restrict__ psib, float* __restrict__ ac){
  __shared__ double d1[128], d2[128];
  int b = blockIdx.x, t = threadIdx.x;
  d1[t] = ps[(b * 128 + t) * 2 + 0];
  d2[t] = ps[(b * 128 + t) * 2 + 1];
  __syncthreads();
  for (int o = 64; o > 0; o >>= 1){
    if (t < o){ d1[t] += d1[t + o]; d2[t] += d2[t + o]; }
    __syncthreads();
  }
  if (t == 0){
    double mean = d1[0] * (1.0 / 262144.0);
    double var  = d2[0] * (1.0 / 262144.0) - mean * mean;
    float a = psig[0] / (float)sqrt(var + 1e-3);
    ac[b * 2 + 0] = a;
    ac[b * 2 + 1] = psib[0] - (float)mean * a;
  }
}

// ---------- row softmax: P[b][s][t] bf16 ----------
__global__ void __launch_bounds__(256) dra_soft(const float* __restrict__ sim,
    const float* __restrict__ ac, uint16_t* __restrict__ P){
  int srow = blockIdx.x, b = blockIdx.y, t = threadIdx.x;
  const float* row = sim + (size_t)b * 262144 + (size_t)srow * 512;
  float a = ac[b * 2], c = ac[b * 2 + 1];
  float v0 = row[t] * a + c, v1 = row[t + 256] * a + c;
  __shared__ float red[256];
  red[t] = fmaxf(v0, v1);
  __syncthreads();
  for (int o = 128; o > 0; o >>= 1){
    if (t < o) red[t] = fmaxf(red[t], red[t + o]);
    __syncthreads();
  }
  float m = red[0];
  __syncthreads();
  float e0 = __expf(v0 - m), e1 = __expf(v1 - m);
  red[t] = e0 + e1;
  __syncthreads();
  for (int o = 128; o > 0; o >>= 1){
    if (t < o) red[t] += red[t + o];
    __syncthreads();
  }
  float inv = 1.f / red[0];
  uint16_t* pr = P + (size_t)b * 262144 + (size_t)srow * 512;
  pr[t] = f2bf(e0 * inv); pr[t + 256] = f2bf(e1 * inv);
}

// ---------- K3: mask conv + BN1 + ReLU, fused x recon-upsample -> out (round-5 best) ----------
__global__ void __launch_bounds__(256, 4) dra_k3(const uint16_t* __restrict__ decT,
    const uint16_t* __restrict__ mcw, const float* __restrict__ s1,
    const float* __restrict__ o1, const float* __restrict__ recon,
    float* __restrict__ outp)
{
  __shared__ uint16_t lA[128 * 32];
  __shared__ uint16_t lB[128 * 32];
  int t = threadIdx.x;
  int L = blockIdx.x;
  int x = L & 7, n = L >> 3;          // n in [0,392)
  int co_t = n & 3, pg = n >> 2;      // pg in [0,98)
  int p = pg * 8 + x;                 // pos-tile x batch, pinned to xcd x
  int bz = p / 98, pt = p - bz * 98;
  int bco  = co_t * 128;
  int pos0 = pt * 128;
  int lane = t & 63, w = t >> 6;
  int wm = w >> 1, wn = w & 1;
  int lr = lane & 15, lg = lane >> 4;

  const uint16_t* aB[2]; const uint16_t* bB[2]; int uu[2];
  #pragma unroll
  for (int i = 0; i < 2; i++){
    int u = t + i * 256; uu[i] = u;
    int row = u >> 2, h = u & 3;
    aB[i] = mcw  + (size_t)(bco + row) * 512 + h * 8;
    bB[i] = decT + ((size_t)bz * 12544 + pos0 + row) * 512 + h * 8;
  }

  const v4f vzero = {0.f,0.f,0.f,0.f};
  v4f acc[4][4];
  #pragma unroll
  for (int i = 0; i < 4; i++)
    #pragma unroll
    for (int j = 0; j < 4; j++) acc[i][j] = vzero;

  for (int k0 = 0; k0 < 512; k0 += 32){
    gl16(aB[0] + k0, &lA[uu[0] * 8]);
    gl16(aB[1] + k0, &lA[uu[1] * 8]);
    gl16(bB[0] + k0, &lB[uu[0] * 8]);
    gl16(bB[1] + k0, &lB[uu[1] * 8]);
    __syncthreads();
    v8s av[4], bv[4];
    #pragma unroll
    for (int mf = 0; mf < 4; mf++) av[mf] = *(const v8s*)&lA[(wm*64 + mf*16 + lr) * 32 + lg * 8];
    #pragma unroll
    for (int nf = 0; nf < 4; nf++) bv[nf] = *(const v8s*)&lB[(wn*64 + nf*16 + lr) * 32 + lg * 8];
    #pragma unroll
    for (int mf = 0; mf < 4; mf++)
      #pragma unroll
      for (int nf = 0; nf < 4; nf++)
        acc[mf][nf] = __builtin_amdgcn_mfma_f32_16x16x32_bf16(av[mf], bv[nf], acc[mf][nf], 0, 0, 0);
    __syncthreads();
  }

  #pragma unroll
  for (int mf = 0; mf < 4; mf++){
    #pragma unroll
    for (int r = 0; r < 4; r++){
      int co = bco + wm*64 + mf*16 + lg*4 + r;
      float sc = s1[co], of = o1[co];
      const float* rrow = recon + (size_t)co * 1792 + bz * 224;
      #pragma unroll
      for (int nf = 0; nf < 4; nf++){
        int pos = pos0 + wn*64 + nf*16 + lr;
        int h = pos / 112, wd = pos - h * 112;
        int pcol = (h >> 3) * 14 + (wd >> 3);
        float mask = fmaxf(acc[mf][nf][r] * sc + of, 0.f);
        outp[((size_t)(bz * 512 + co)) * 12544 + pos] = mask * rrow[pcol];
      }
    }
  }
}

// ---------- launch ----------
extern "C" void kernel_launch(void* const* d_in, const int* in_sizes, int n_in,
                              void* d_out, int out_size, void* d_ws, size_t ws_size,
                              hipStream_t stream) {
  (void)in_sizes; (void)n_in; (void)out_size; (void)ws_size;
  const float* dec   = (const float*)d_in[0];
  const float* trans = (const float*)d_in[1];
  const float* pe_w  = (const float*)d_in[2];
  const float* pe_b  = (const float*)d_in[3];
  const float* mc_w  = (const float*)d_in[4];
  const float* mc_b  = (const float*)d_in[5];
  const float* bn1g  = (const float*)d_in[6];
  const float* bn1b  = (const float*)d_in[7];
  const float* bn1m  = (const float*)d_in[8];
  const float* bn1v  = (const float*)d_in[9];
  const float* wq    = (const float*)d_in[10];
  const float* wk    = (const float*)d_in[11];
  const float* wv    = (const float*)d_in[12];
  const float* wo    = (const float*)d_in[13];
  const float* psig  = (const float*)d_in[14];
  const float* psib  = (const float*)d_in[15];
  const float* rc_w  = (const float*)d_in[16];
  const float* rc_b  = (const float*)d_in[17];
  const float* bn2g  = (const float*)d_in[18];
  const float* bn2b  = (const float*)d_in[19];
  const float* bn2m  = (const float*)d_in[20];
  const float* bn2v  = (const float*)d_in[21];

  char* p = (char*)d_ws;
  auto take = [&](size_t bytes) -> void* {
    void* r = (void*)p; p += (bytes + 255) & ~(size_t)255; return r;
  };
  uint16_t* decT   = (uint16_t*)take((size_t)8 * 12544 * 512 * 2);   // 102.8 MB
  uint16_t* wpe2   = (uint16_t*)take((size_t)512 * 32768 * 2);       // 33.5 MB
  uint16_t* mcw    = (uint16_t*)take((size_t)512 * 512 * 2);
  uint16_t* rcw    = (uint16_t*)take((size_t)512 * 512 * 2);
  uint16_t* wqT    = (uint16_t*)take((size_t)512 * 512 * 2);
  uint16_t* woT    = (uint16_t*)take((size_t)512 * 512 * 2);
  uint16_t* wkT    = (uint16_t*)take((size_t)512 * 768 * 2);
  uint16_t* wvT    = (uint16_t*)take((size_t)512 * 768 * 2);
  uint16_t* transb = (uint16_t*)take((size_t)1792 * 768 * 2);
  float*    s1v    = (float*)take(512 * 4);
  float*    o1v    = (float*)take(512 * 4);
  float*    s2v    = (float*)take(512 * 4);
  float*    o2v    = (float*)take(512 * 4);
  uint16_t* dlb    = (uint16_t*)take((size_t)1792 * 512 * 2);
  uint16_t* Qt     = (uint16_t*)take((size_t)512 * 1792 * 2);
  uint16_t* Kt     = (uint16_t*)take((size_t)512 * 1792 * 2);
  uint16_t* Vb     = (uint16_t*)take((size_t)1792 * 512 * 2);
  float*    ac     = (float*)take(256);
  double*   ps     = (double*)take((size_t)8 * 128 * 2 * 8);         // 16 KB stats partials
  float*    part   = (float*)take((size_t)16 * 1792 * 512 * 4);      // 58.7 MB
  // alias attention temps inside part (consumed by dra_red before these are written)
  float*    simb   = part;                                            // 8.39 MB
  uint16_t* P      = (uint16_t*)(part + 2097152);                     // 4.19 MB
  uint16_t* outb   = P + 2097152;                                     // 1.84 MB
  uint16_t* out2   = outb + 917504;                                   // 1.84 MB
  float*    recon  = (float*)(out2 + 917504);                         // 3.67 MB

  // fused prep (tdec + wpe2 + cvt x2 + tcvt x4 + transb + scales)
  dra_prep<<<22306, 256, 0, stream>>>(dec, decT, pe_w, wpe2, mc_w, mcw, rc_w, rcw,
      wq, wqT, wk, wkT, wv, wvT, wo, woT, trans, transb,
      mc_b, bn1g, bn1b, bn1m, bn1v, rc_b, bn2g, bn2b, bn2m, bn2v,
      s1v, o1v, s2v, o2v);

  // patch embedding: split-K partials + reduce (-> dlb bf16)
  dra_k1<<<896, 256, 0, stream>>>(decT, wpe2, part);
  dra_red<<<448, 256, 0, stream>>>(part, pe_b, dlb);

  // Qt[s][n] ; Kt[t][n] ; Vb[n][t]
  dra_gemm<2><<<dim3(8, 28, 1), 256, 0, stream>>>(wqT, dlb, Qt, 512, 1792, 512,
      512, 512, 1792, 0, 0, 0, 1, nullptr, nullptr);
  dra_gemm<2><<<dim3(8, 28, 1), 256, 0, stream>>>(wkT, transb, Kt, 512, 1792, 768,
      768, 768, 1792, 0, 0, 0, 1, nullptr, nullptr);
  dra_gemm<2><<<dim3(28, 8, 1), 256, 0, stream>>>(transb, wvT, Vb, 1792, 512, 768,
      768, 768, 512, 0, 0, 0, 1, nullptr, nullptr);

  // sim = Qt x Kt over padded tokens (zeros in pad cols of Kt)
  dra_gemm<2><<<dim3(8, 8, 8), 256, 0, stream>>>(Qt, Kt, simb, 512, 512, 224,
      1792, 1792, 512, 224, 224, 262144, 0, nullptr, nullptr);
  dra_stats1<<<dim3(128, 8), 256, 0, stream>>>(simb, ps);
  dra_stats2<<<8, 128, 0, stream>>>(ps, psig, psib, ac);
  dra_soft<<<dim3(512, 8), 256, 0, stream>>>(simb, ac, P);

  // out = P x V ; out2 = out x wo ; recon = relu(bn2(rc(out2)))
  dra_gemm<2><<<dim3(4, 8, 8), 256, 0, stream>>>(Vb, P, outb, 224, 512, 512,
      512, 512, 512, 114688, 262144, 114688, 1, nullptr, nullptr);
  dra_gemm<2><<<dim3(28, 8, 1), 256, 0, stream>>>(outb, woT, out2, 1792, 512, 512,
      512, 512, 512, 0, 0, 0, 1, nullptr, nullptr);
  dra_gemm<2><<<dim3(8, 28, 1), 256, 0, stream>>>(rcw, out2, recon, 512, 1792, 512,
      512, 512, 1792, 0, 0, 0, 2, s2v, o2v);

  // mask conv + BN1 + ReLU, x upsampled recon -> final output
  dra_k3<<<3136, 256, 0, stream>>>(decT, mcw, s1v, o1v, recon, (float*)d_out);
}

// Round 15
// 390.499 us; speedup vs baseline: 1.0279x; 1.0279x over previous
//
#include <hip/hip_runtime.h>
#include <stdint.h>

// ---------- types & helpers ----------
typedef __attribute__((ext_vector_type(8))) short v8s;   // 8 x bf16 (4 VGPRs)
typedef __attribute__((ext_vector_type(4))) float v4f;   // MFMA C/D frag

__device__ __forceinline__ uint16_t f2bf(float x){
  uint32_t u = __float_as_uint(x);
  return (uint16_t)((u + 0x7FFFu + ((u >> 16) & 1u)) >> 16);  // RNE
}
__device__ __forceinline__ uint32_t pk2(float a, float b){
  return (uint32_t)f2bf(a) | ((uint32_t)f2bf(b) << 16);
}

// async global->LDS, 16B per lane. LDS dest is wave-uniform-base + lane*16 (linear).
__device__ __forceinline__ void gl16(const uint16_t* g, uint16_t* l){
  __builtin_amdgcn_global_load_lds((const __attribute__((address_space(1))) void*)g,
                                   (__attribute__((address_space(3))) void*)l, 16, 0, 0);
}

// ---------- fused prep: one launch, block-range dispatch over 10 independent jobs ----------
// [0,3136)       tdec    : dec f32 NCHW -> decT bf16 [b][pos][ci]  (128x128 tile, rot-swizzle)
// [3136,11328)   wpe2    : pe_w -> [co][pix*512+ci] bf16
// [11328,11456)  cvt mcw ; [11456,11584) cvt rcw
// [11584,11712)  tcvt wq ; [11712,11904) tcvt wk ; [11904,12096) tcvt wv ; [12096,12224) tcvt wo
// [12224,12896)  transb  ; [12896,12898) scales
__device__ __forceinline__ void prep_cvt(const float* s, uint16_t* d, int id, int n8){
  if (id >= n8) return;
  const float4* sp = (const float4*)(s + (size_t)id * 8);
  float4 f0 = sp[0], f1 = sp[1];
  uint4 u; u.x = pk2(f0.x, f0.y); u.y = pk2(f0.z, f0.w);
  u.z = pk2(f1.x, f1.y); u.w = pk2(f1.z, f1.w);
  *(uint4*)(d + (size_t)id * 8) = u;
}
__device__ __forceinline__ void prep_tcvt(const float* s, uint16_t* d, int id, int R, int C){
  int r8 = R >> 3;
  if (id >= C * r8) return;
  int c = id / r8, r0 = (id - c * r8) * 8;
  float v[8];
  #pragma unroll
  for (int e = 0; e < 8; e++) v[e] = s[(size_t)(r0 + e) * C + c];
  uint4 u; u.x = pk2(v[0], v[1]); u.y = pk2(v[2], v[3]);
  u.z = pk2(v[4], v[5]); u.w = pk2(v[6], v[7]);
  *(uint4*)(d + (size_t)c * R + r0) = u;
}

__global__ void __launch_bounds__(256) dra_prep(
    const float* __restrict__ dec, uint16_t* __restrict__ decT,
    const float* __restrict__ pw, uint16_t* __restrict__ w2,
    const float* __restrict__ mc_w, uint16_t* __restrict__ mcw,
    const float* __restrict__ rc_w, uint16_t* __restrict__ rcw,
    const float* __restrict__ wq, uint16_t* __restrict__ wqT,
    const float* __restrict__ wk, uint16_t* __restrict__ wkT,
    const float* __restrict__ wv, uint16_t* __restrict__ wvT,
    const float* __restrict__ wo, uint16_t* __restrict__ woT,
    const float* __restrict__ tr, uint16_t* __restrict__ transb,
    const float* __restrict__ mcb, const float* __restrict__ g1, const float* __restrict__ b1,
    const float* __restrict__ m1, const float* __restrict__ v1,
    const float* __restrict__ rcb, const float* __restrict__ g2, const float* __restrict__ b2,
    const float* __restrict__ m2, const float* __restrict__ v2,
    float* __restrict__ s1, float* __restrict__ o1, float* __restrict__ s2, float* __restrict__ o2)
{
  __shared__ uint16_t lt[128 * 128];   // [pos][ci] 32KB, 16-block rotation swizzle
  int B = blockIdx.x, t = threadIdx.x;

  if (B < 3136){                                    // ---- tdec (128 pos x 128 ci tile) ----
    int pos0 = (B % 98) * 128;
    int ci0  = ((B / 98) & 3) * 128;
    int b    = B / 392;
    // write: element (p,c) -> lt[p*128 + (((c>>3)+(p>>2))&15)*8 + (c&7)]
    #pragma unroll
    for (int i = 0; i < 16; i++){
      int u = t + i * 256;
      int ci_l = u >> 5, p4 = (u & 31) * 4;
      const float4 f = *(const float4*)(dec + ((size_t)(b * 512 + ci0 + ci_l)) * 12544 + pos0 + p4);
      float v[4] = {f.x, f.y, f.z, f.w};
      #pragma unroll
      for (int j = 0; j < 4; j++){
        int p = p4 + j;
        int bp = ((ci_l >> 3) + (p >> 2)) & 15;
        lt[p * 128 + bp * 8 + (ci_l & 7)] = f2bf(v[j]);
      }
    }
    __syncthreads();
    // read: logical block u of row p_l at physical block (u+(p_l>>2))&15 (order preserved)
    #pragma unroll
    for (int i = 0; i < 8; i++){
      int idx = t + i * 256;
      int p_l = idx >> 4, u = idx & 15;
      int bp = (u + (p_l >> 2)) & 15;
      uint4 v = *(const uint4*)&lt[p_l * 128 + bp * 8];
      *(uint4*)(decT + ((size_t)b * 12544 + pos0 + p_l) * 512 + ci0 + u * 8) = v;
    }
  } else if (B < 11328){                            // ---- wpe2 ----
    int id = (B - 3136) * 256 + t;
    if (id < 2097152){
      int co = id >> 12, rem = id & 4095;
      int ci8 = rem >> 6, pix = rem & 63;
      const float* s = pw + (size_t)co * 32768 + ci8 * 512 + pix;
      float v[8];
      #pragma unroll
      for (int j = 0; j < 8; j++) v[j] = s[j * 64];
      uint4 u; u.x = pk2(v[0], v[1]); u.y = pk2(v[2], v[3]);
      u.z = pk2(v[4], v[5]); u.w = pk2(v[6], v[7]);
      *(uint4*)(w2 + (size_t)co * 32768 + pix * 512 + ci8 * 8) = u;
    }
  } else if (B < 11456){ prep_cvt(mc_w, mcw, (B - 11328) * 256 + t, 32768); }
  else if (B < 11584){ prep_cvt(rc_w, rcw, (B - 11456) * 256 + t, 32768); }
  else if (B < 11712){ prep_tcvt(wq, wqT, (B - 11584) * 256 + t, 512, 512); }
  else if (B < 11904){ prep_tcvt(wk, wkT, (B - 11712) * 256 + t, 768, 512); }
  else if (B < 12096){ prep_tcvt(wv, wvT, (B - 11904) * 256 + t, 768, 512); }
  else if (B < 12224){ prep_tcvt(wo, woT, (B - 12096) * 256 + t, 512, 512); }
  else if (B < 12896){                              // ---- transb ----
    int id = (B - 12224) * 256 + t;
    if (id < 1792 * 96){
      int n = id / 96, e0 = (id - n * 96) * 8;
      int b = n / 224, nl = n - b * 224;
      uint4 u = {0u,0u,0u,0u};
      if (nl < 196){
        const float* sp = tr + ((size_t)(b * 196 + nl)) * 768 + e0;
        u.x = pk2(sp[0], sp[1]); u.y = pk2(sp[2], sp[3]);
        u.z = pk2(sp[4], sp[5]); u.w = pk2(sp[6], sp[7]);
      }
      *(uint4*)(transb + (size_t)n * 768 + e0) = u;
    }
  } else {                                          // ---- scales ----
    int i = (B - 12896) * 256 + t;
    if (i < 512){
      float sc1 = g1[i] / sqrtf(v1[i] + 1e-3f);
      s1[i] = sc1; o1[i] = (mcb[i] - m1[i]) * sc1 + b1[i];
      float sc2 = g2[i] / sqrtf(v2[i] + 1e-3f);
      s2[i] = sc2; o2[i] = (rcb[i] - m2[i]) * sc2 + b2[i];
    }
  }
}

// ---------- K1: patch-embed as split-K GEMM with partial buffers (round-5 best) ----------
__global__ void __launch_bounds__(256, 4) dra_k1(const uint16_t* __restrict__ decT,
    const uint16_t* __restrict__ wpe2, float* __restrict__ part)
{
  __shared__ uint16_t lA[128 * 32];
  __shared__ uint16_t lB[128 * 32];
  int t = threadIdx.x;
  int L = blockIdx.x;
  int x = L & 7, n = L >> 3;           // n in [0,112)
  int shi = n / 56, rem = n - shi * 56;
  int tok_t = rem >> 2, co_t = rem & 3;
  int s    = shi * 8 + x;              // split 0..15 pinned to xcd x
  int bco  = co_t * 128;
  int tok0 = tok_t * 128;
  int lane = t & 63, w = t >> 6;
  int wm = w >> 1, wn = w & 1;
  int lr = lane & 15, lg = lane >> 4;

  const uint16_t* aB[2]; const uint16_t* bB[2]; int uu[2];
  #pragma unroll
  for (int i = 0; i < 2; i++){
    int u = t + i * 256; uu[i] = u;
    int row = u >> 2, h = u & 3;
    int token = tok0 + row;
    int b = token / 224, tl = token - b * 224;
    if (tl > 195) tl = 195;                       // clamp pad tokens (finite garbage, unused later)
    int py = tl / 14, px = tl - py * 14;
    aB[i] = decT + ((size_t)b * 12544 + py * 896 + px * 8) * 512 + h * 8;
    bB[i] = wpe2 + (size_t)(bco + row) * 32768 + h * 8;
  }

  const v4f vzero = {0.f,0.f,0.f,0.f};
  v4f acc[4][4];
  #pragma unroll
  for (int i = 0; i < 4; i++)
    #pragma unroll
    for (int j = 0; j < 4; j++) acc[i][j] = vzero;

  for (int pix = s * 4; pix < s * 4 + 4; ++pix){
    int ky = pix >> 3, kx = pix & 7;
    int poff = (ky * 112 + kx) * 512;
    int k0p  = pix * 512;
    for (int ci0 = 0; ci0 < 512; ci0 += 32){
      gl16(aB[0] + poff + ci0, &lA[uu[0] * 8]);
      gl16(aB[1] + poff + ci0, &lA[uu[1] * 8]);
      gl16(bB[0] + k0p + ci0,  &lB[uu[0] * 8]);
      gl16(bB[1] + k0p + ci0,  &lB[uu[1] * 8]);
      __syncthreads();
      v8s av[4], bv[4];
      #pragma unroll
      for (int mf = 0; mf < 4; mf++) av[mf] = *(const v8s*)&lA[(wm*64 + mf*16 + lr) * 32 + lg * 8];
      #pragma unroll
      for (int nf = 0; nf < 4; nf++) bv[nf] = *(const v8s*)&lB[(wn*64 + nf*16 + lr) * 32 + lg * 8];
      #pragma unroll
      for (int mf = 0; mf < 4; mf++)
        #pragma unroll
        for (int nf = 0; nf < 4; nf++)
          acc[mf][nf] = __builtin_amdgcn_mfma_f32_16x16x32_bf16(av[mf], bv[nf], acc[mf][nf], 0, 0, 0);
      __syncthreads();
    }
  }
  float* pd = part + (size_t)s * 917504;
  #pragma unroll
  for (int mf = 0; mf < 4; mf++){
    #pragma unroll
    for (int nf = 0; nf < 4; nf++){
      int tokg = tok0 + wm*64 + mf*16 + lg*4;
      int cog  = bco  + wn*64 + nf*16 + lr;
      #pragma unroll
      for (int r = 0; r < 4; r++)
        pd[(size_t)(tokg + r) * 512 + cog] = acc[mf][nf][r];
    }
  }
}

// reduce 16 split partials + bias -> dlb bf16 [1792][512]
__global__ void __launch_bounds__(256) dra_red(const float* __restrict__ part,
    const float* __restrict__ peb, uint16_t* __restrict__ dlb){
  int id = blockIdx.x * 256 + threadIdx.x;
  if (id >= 114688) return;
  int tok = id >> 6, c8 = (id & 63) * 8;
  float a0=0,a1=0,a2=0,a3=0,a4=0,a5=0,a6=0,a7=0;
  #pragma unroll
  for (int s = 0; s < 16; s++){
    const float* p = part + (size_t)s * 917504 + (size_t)tok * 512 + c8;
    float4 x = *(const float4*)p, y = *(const float4*)(p + 4);
    a0 += x.x; a1 += x.y; a2 += x.z; a3 += x.w;
    a4 += y.x; a5 += y.y; a6 += y.z; a7 += y.w;
  }
  const float4 b0 = *(const float4*)(peb + c8), b1 = *(const float4*)(peb + c8 + 4);
  uint4 o; o.x = pk2(a0 + b0.x, a1 + b0.y); o.y = pk2(a2 + b0.z, a3 + b0.w);
  o.z = pk2(a4 + b1.x, a5 + b1.y); o.w = pk2(a6 + b1.z, a7 + b1.w);
  *(uint4*)(dlb + (size_t)tok * 512 + c8) = o;
}

// ---------- generic NT GEMM (attention chain): D[m][n] = sum_k A[m][k]*B[n][k] ----------
// BM = MREP*32, BN=64, BK=32, 256 threads (2x2 waves). Staging via global_load_lds with
// source-chunk swizzle c^((row>>1)&3): even rows cycle all 4 slots -> 2 lanes/bank (free).
template<int MREP>
__global__ void __launch_bounds__(256, 2) dra_gemm(
    const uint16_t* __restrict__ A, const uint16_t* __restrict__ Bn, void* __restrict__ Dv,
    int M, int N, int K, int lda, int ldb, int ldd,
    long long sAz, long long sBz, long long sDz,
    int epi, const float* __restrict__ svec, const float* __restrict__ ovec)
{
  constexpr int BM = MREP * 32;
  __shared__ uint16_t lA[BM * 32];
  __shared__ uint16_t lB[64 * 32];
  int t = threadIdx.x, z = blockIdx.z;
  int bm = blockIdx.x * BM, bn = blockIdx.y * 64;
  const uint16_t* Az = A + (size_t)z * sAz;
  const uint16_t* Bz = Bn + (size_t)z * sBz;
  int lane = t & 63, w = t >> 6;
  int wm = w >> 1, wn = w & 1;
  int lr = lane & 15, lg = lane >> 4;

  const uint16_t* aSrc[MREP/2]; int uuA[MREP/2];
  #pragma unroll
  for (int i = 0; i < MREP/2; i++){
    int u = t + i * 256; uuA[i] = u;
    int row = u >> 2, c = u & 3;
    int cs = c ^ ((row >> 1) & 3);
    int rg = bm + row; if (rg >= M) rg = M - 1;
    aSrc[i] = Az + (size_t)rg * lda + cs * 8;
  }
  const uint16_t* bSrc;
  {
    int row = t >> 2, c = t & 3;
    int cs = c ^ ((row >> 1) & 3);
    bSrc = Bz + (size_t)(bn + row) * ldb + cs * 8;
  }

  int aoff[MREP], boff[2];
  #pragma unroll
  for (int mf = 0; mf < MREP; mf++){
    int R = wm*(MREP*16) + mf*16 + lr;
    aoff[mf] = R * 32 + (lg ^ ((R >> 1) & 3)) * 8;
  }
  #pragma unroll
  for (int nf = 0; nf < 2; nf++){
    int R = wn*32 + nf*16 + lr;
    boff[nf] = R * 32 + (lg ^ ((R >> 1) & 3)) * 8;
  }

  const v4f vzero = {0.f, 0.f, 0.f, 0.f};
  v4f acc[MREP][2];
  #pragma unroll
  for (int i = 0; i < MREP; i++){ acc[i][0] = vzero; acc[i][1] = vzero; }

  for (int k0 = 0; k0 < K; k0 += 32){
    #pragma unroll
    for (int i = 0; i < MREP/2; i++)
      gl16(aSrc[i] + k0, &lA[uuA[i] * 8]);
    gl16(bSrc + k0, &lB[t * 8]);
    __syncthreads();
    v8s av[MREP], bv[2];
    #pragma unroll
    for (int mf = 0; mf < MREP; mf++) av[mf] = *(const v8s*)&lA[aoff[mf]];
    #pragma unroll
    for (int nf = 0; nf < 2; nf++)    bv[nf] = *(const v8s*)&lB[boff[nf]];
    #pragma unroll
    for (int mf = 0; mf < MREP; mf++)
      #pragma unroll
      for (int nf = 0; nf < 2; nf++)
        acc[mf][nf] = __builtin_amdgcn_mfma_f32_16x16x32_bf16(av[mf], bv[nf], acc[mf][nf], 0, 0, 0);
    __syncthreads();
  }

  #pragma unroll
  for (int mf = 0; mf < MREP; mf++){
    #pragma unroll
    for (int nf = 0; nf < 2; nf++){
      int mg0 = bm + wm*(MREP*16) + mf*16 + lg*4;
      int ng  = bn + wn*32 + nf*16 + lr;
      #pragma unroll
      for (int r = 0; r < 4; r++){
        int mg = mg0 + r;
        if (mg < M){
          float val = acc[mf][nf][r];
          size_t di = (size_t)z * sDz + (size_t)mg * ldd + ng;
          if (epi == 0)      ((float*)Dv)[di] = val;
          else if (epi == 1) ((uint16_t*)Dv)[di] = f2bf(val);
          else ((float*)Dv)[di] = fmaxf(val * svec[mg] + ovec[mg], 0.f);
        }
      }
    }
  }
}

// ---------- InstanceNorm stats: two-stage deterministic tree reduction ----------
__global__ void __launch_bounds__(256) dra_stats1(const float* __restrict__ sim,
                                                  double* __restrict__ ps){
  __shared__ double d1[256], d2[256];
  int b = blockIdx.y, blk = blockIdx.x, t = threadIdx.x;
  const float* s = sim + (size_t)b * 262144 + (size_t)blk * 2048 + t * 8;
  float4 x = *(const float4*)s, y = *(const float4*)(s + 4);
  double p1 = (double)x.x + x.y + x.z + x.w + y.x + y.y + y.z + y.w;
  double p2 = (double)x.x*x.x + (double)x.y*x.y + (double)x.z*x.z + (double)x.w*x.w
            + (double)y.x*y.x + (double)y.y*y.y + (double)y.z*y.z + (double)y.w*y.w;
  d1[t] = p1; d2[t] = p2;
  __syncthreads();
  for (int o = 128; o > 0; o >>= 1){
    if (t < o){ d1[t] += d1[t + o]; d2[t] += d2[t + o]; }
    __syncthreads();
  }
  if (t == 0){
    ps[(b * 128 + blk) * 2 + 0] = d1[0];
    ps[(b * 128 + blk) * 2 + 1] = d2[0];
  }
}

__global__ void __launch_bounds__(128) dra_stats2(const double* __restrict__ ps,
    const float* __restrict__ psig, const float* __restrict__ psib, float* __restrict__ ac){
  __shared__ double d1[128], d2[128];
  int b = blockIdx.x, t = threadIdx.x;
  d1[t] = ps[(b * 128 + t) * 2 + 0];
  d2[t] = ps[(b * 128 + t) * 2 + 1];
  __syncthreads();
  for (int o = 64; o > 0; o >>= 1){
    if (t < o){ d1[t] += d1[t + o]; d2[t] += d2[t + o]; }
    __syncthreads();
  }
  if (t == 0){
    double mean = d1[0] * (1.0 / 262144.0);
    double var  = d2[0] * (1.0 / 262144.0) - mean * mean;
    float a = psig[0] / (float)sqrt(var + 1e-3);
    ac[b * 2 + 0] = a;
    ac[b * 2 + 1] = psib[0] - (float)mean * a;
  }
}

// ---------- row softmax: P[b][s][t] bf16 ----------
__global__ void __launch_bounds__(256) dra_soft(const float* __restrict__ sim,
    const float* __restrict__ ac, uint16_t* __restrict__ P){
  int srow = blockIdx.x, b = blockIdx.y, t = threadIdx.x;
  const float* row = sim + (size_t)b * 262144 + (size_t)srow * 512;
  float a = ac[b * 2], c = ac[b * 2 + 1];
  float v0 = row[t] * a + c, v1 = row[t + 256] * a + c;
  __shared__ float red[256];
  red[t] = fmaxf(v0, v1);
  __syncthreads();
  for (int o = 128; o > 0; o >>= 1){
    if (t < o) red[t] = fmaxf(red[t], red[t + o]);
    __syncthreads();
  }
  float m = red[0];
  __syncthreads();
  float e0 = __expf(v0 - m), e1 = __expf(v1 - m);
  red[t] = e0 + e1;
  __syncthreads();
  for (int o = 128; o > 0; o >>= 1){
    if (t < o) red[t] += red[t + o];
    __syncthreads();
  }
  float inv = 1.f / red[0];
  uint16_t* pr = P + (size_t)b * 262144 + (size_t)srow * 512;
  pr[t] = f2bf(e0 * inv); pr[t + 256] = f2bf(e1 * inv);
}

// ---------- K3: mask conv + BN1 + ReLU, fused x recon-upsample -> out (round-5 best) ----------
__global__ void __launch_bounds__(256, 4) dra_k3(const uint16_t* __restrict__ decT,
    const uint16_t* __restrict__ mcw, const float* __restrict__ s1,
    const float* __restrict__ o1, const float* __restrict__ recon,
    float* __restrict__ outp)
{
  __shared__ uint16_t lA[128 * 32];
  __shared__ uint16_t lB[128 * 32];
  int t = threadIdx.x;
  int L = blockIdx.x;
  int x = L & 7, n = L >> 3;          // n in [0,392)
  int co_t = n & 3, pg = n >> 2;      // pg in [0,98)
  int p = pg * 8 + x;                 // pos-tile x batch, pinned to xcd x
  int bz = p / 98, pt = p - bz * 98;
  int bco  = co_t * 128;
  int pos0 = pt * 128;
  int lane = t & 63, w = t >> 6;
  int wm = w >> 1, wn = w & 1;
  int lr = lane & 15, lg = lane >> 4;

  const uint16_t* aB[2]; const uint16_t* bB[2]; int uu[2];
  #pragma unroll
  for (int i = 0; i < 2; i++){
    int u = t + i * 256; uu[i] = u;
    int row = u >> 2, h = u & 3;
    aB[i] = mcw  + (size_t)(bco + row) * 512 + h * 8;
    bB[i] = decT + ((size_t)bz * 12544 + pos0 + row) * 512 + h * 8;
  }

  const v4f vzero = {0.f,0.f,0.f,0.f};
  v4f acc[4][4];
  #pragma unroll
  for (int i = 0; i < 4; i++)
    #pragma unroll
    for (int j = 0; j < 4; j++) acc[i][j] = vzero;

  for (int k0 = 0; k0 < 512; k0 += 32){
    gl16(aB[0] + k0, &lA[uu[0] * 8]);
    gl16(aB[1] + k0, &lA[uu[1] * 8]);
    gl16(bB[0] + k0, &lB[uu[0] * 8]);
    gl16(bB[1] + k0, &lB[uu[1] * 8]);
    __syncthreads();
    v8s av[4], bv[4];
    #pragma unroll
    for (int mf = 0; mf < 4; mf++) av[mf] = *(const v8s*)&lA[(wm*64 + mf*16 + lr) * 32 + lg * 8];
    #pragma unroll
    for (int nf = 0; nf < 4; nf++) bv[nf] = *(const v8s*)&lB[(wn*64 + nf*16 + lr) * 32 + lg * 8];
    #pragma unroll
    for (int mf = 0; mf < 4; mf++)
      #pragma unroll
      for (int nf = 0; nf < 4; nf++)
        acc[mf][nf] = __builtin_amdgcn_mfma_f32_16x16x32_bf16(av[mf], bv[nf], acc[mf][nf], 0, 0, 0);
    __syncthreads();
  }

  #pragma unroll
  for (int mf = 0; mf < 4; mf++){
    #pragma unroll
    for (int r = 0; r < 4; r++){
      int co = bco + wm*64 + mf*16 + lg*4 + r;
      float sc = s1[co], of = o1[co];
      const float* rrow = recon + (size_t)co * 1792 + bz * 224;
      #pragma unroll
      for (int nf = 0; nf < 4; nf++){
        int pos = pos0 + wn*64 + nf*16 + lr;
        int h = pos / 112, wd = pos - h * 112;
        int pcol = (h >> 3) * 14 + (wd >> 3);
        float mask = fmaxf(acc[mf][nf][r] * sc + of, 0.f);
        outp[((size_t)(bz * 512 + co)) * 12544 + pos] = mask * rrow[pcol];
      }
    }
  }
}

// ---------- launch ----------
extern "C" void kernel_launch(void* const* d_in, const int* in_sizes, int n_in,
                              void* d_out, int out_size, void* d_ws, size_t ws_size,
                              hipStream_t stream) {
  (void)in_sizes; (void)n_in; (void)out_size; (void)ws_size;
  const float* dec   = (const float*)d_in[0];
  const float* trans = (const float*)d_in[1];
  const float* pe_w  = (const float*)d_in[2];
  const float* pe_b  = (const float*)d_in[3];
  const float* mc_w  = (const float*)d_in[4];
  const float* mc_b  = (const float*)d_in[5];
  const float* bn1g  = (const float*)d_in[6];
  const float* bn1b  = (const float*)d_in[7];
  const float* bn1m  = (const float*)d_in[8];
  const float* bn1v  = (const float*)d_in[9];
  const float* wq    = (const float*)d_in[10];
  const float* wk    = (const float*)d_in[11];
  const float* wv    = (const float*)d_in[12];
  const float* wo    = (const float*)d_in[13];
  const float* psig  = (const float*)d_in[14];
  const float* psib  = (const float*)d_in[15];
  const float* rc_w  = (const float*)d_in[16];
  const float* rc_b  = (const float*)d_in[17];
  const float* bn2g  = (const float*)d_in[18];
  const float* bn2b  = (const float*)d_in[19];
  const float* bn2m  = (const float*)d_in[20];
  const float* bn2v  = (const float*)d_in[21];

  char* p = (char*)d_ws;
  auto take = [&](size_t bytes) -> void* {
    void* r = (void*)p; p += (bytes + 255) & ~(size_t)255; return r;
  };
  uint16_t* decT   = (uint16_t*)take((size_t)8 * 12544 * 512 * 2);   // 102.8 MB
  uint16_t* wpe2   = (uint16_t*)take((size_t)512 * 32768 * 2);       // 33.5 MB
  uint16_t* mcw    = (uint16_t*)take((size_t)512 * 512 * 2);
  uint16_t* rcw    = (uint16_t*)take((size_t)512 * 512 * 2);
  uint16_t* wqT    = (uint16_t*)take((size_t)512 * 512 * 2);
  uint16_t* woT    = (uint16_t*)take((size_t)512 * 512 * 2);
  uint16_t* wkT    = (uint16_t*)take((size_t)512 * 768 * 2);
  uint16_t* wvT    = (uint16_t*)take((size_t)512 * 768 * 2);
  uint16_t* transb = (uint16_t*)take((size_t)1792 * 768 * 2);
  float*    s1v    = (float*)take(512 * 4);
  float*    o1v    = (float*)take(512 * 4);
  float*    s2v    = (float*)take(512 * 4);
  float*    o2v    = (float*)take(512 * 4);
  uint16_t* dlb    = (uint16_t*)take((size_t)1792 * 512 * 2);
  uint16_t* Qt     = (uint16_t*)take((size_t)512 * 1792 * 2);
  uint16_t* Kt     = (uint16_t*)take((size_t)512 * 1792 * 2);
  uint16_t* Vb     = (uint16_t*)take((size_t)1792 * 512 * 2);
  float*    ac     = (float*)take(256);
  double*   ps     = (double*)take((size_t)8 * 128 * 2 * 8);         // 16 KB stats partials
  float*    part   = (float*)take((size_t)16 * 1792 * 512 * 4);      // 58.7 MB
  // alias attention temps inside part (consumed by dra_red before these are written)
  float*    simb   = part;                                            // 8.39 MB
  uint16_t* P      = (uint16_t*)(part + 2097152);                     // 4.19 MB
  uint16_t* outb   = P + 2097152;                                     // 1.84 MB
  uint16_t* out2   = outb + 917504;                                   // 1.84 MB
  float*    recon  = (float*)(out2 + 917504);                         // 3.67 MB

  // fused prep (tdec 128x128 + wpe2 + cvt x2 + tcvt x4 + transb + scales)
  dra_prep<<<12898, 256, 0, stream>>>(dec, decT, pe_w, wpe2, mc_w, mcw, rc_w, rcw,
      wq, wqT, wk, wkT, wv, wvT, wo, woT, trans, transb,
      mc_b, bn1g, bn1b, bn1m, bn1v, rc_b, bn2g, bn2b, bn2m, bn2v,
      s1v, o1v, s2v, o2v);

  // patch embedding: split-K partials + reduce (-> dlb bf16)
  dra_k1<<<896, 256, 0, stream>>>(decT, wpe2, part);
  dra_red<<<448, 256, 0, stream>>>(part, pe_b, dlb);

  // Qt[s][n] ; Kt[t][n] ; Vb[n][t]
  dra_gemm<2><<<dim3(8, 28, 1), 256, 0, stream>>>(wqT, dlb, Qt, 512, 1792, 512,
      512, 512, 1792, 0, 0, 0, 1, nullptr, nullptr);
  dra_gemm<2><<<dim3(8, 28, 1), 256, 0, stream>>>(wkT, transb, Kt, 512, 1792, 768,
      768, 768, 1792, 0, 0, 0, 1, nullptr, nullptr);
  dra_gemm<2><<<dim3(28, 8, 1), 256, 0, stream>>>(transb, wvT, Vb, 1792, 512, 768,
      768, 768, 512, 0, 0, 0, 1, nullptr, nullptr);

  // sim = Qt x Kt over padded tokens (zeros in pad cols of Kt)
  dra_gemm<2><<<dim3(8, 8, 8), 256, 0, stream>>>(Qt, Kt, simb, 512, 512, 224,
      1792, 1792, 512, 224, 224, 262144, 0, nullptr, nullptr);
  dra_stats1<<<dim3(128, 8), 256, 0, stream>>>(simb, ps);
  dra_stats2<<<8, 128, 0, stream>>>(ps, psig, psib, ac);
  dra_soft<<<dim3(512, 8), 256, 0, stream>>>(simb, ac, P);

  // out = P x V ; out2 = out x wo ; recon = relu(bn2(rc(out2)))
  dra_gemm<2><<<dim3(4, 8, 8), 256, 0, stream>>>(Vb, P, outb, 224, 512, 512,
      512, 512, 512, 114688, 262144, 114688, 1, nullptr, nullptr);
  dra_gemm<2><<<dim3(28, 8, 1), 256, 0, stream>>>(outb, woT, out2, 1792, 512, 512,
      512, 512, 512, 0, 0, 0, 1, nullptr, nullptr);
  dra_gemm<2><<<dim3(8, 28, 1), 256, 0, stream>>>(rcw, out2, recon, 512, 1792, 512,
      512, 512, 1792, 0, 0, 0, 2, s2v, o2v);

  // mask conv + BN1 + ReLU, x upsampled recon -> final output
  dra_k3<<<3136, 256, 0, stream>>>(decT, mcw, s1v, o1v, recon, (float*)d_out);
}

// Round 16
// 385.733 us; speedup vs baseline: 1.0406x; 1.0124x over previous
//
#include <hip/hip_runtime.h>
#include <stdint.h>

// ---------- types & helpers ----------
typedef __attribute__((ext_vector_type(8))) short v8s;   // 8 x bf16 (4 VGPRs)
typedef __attribute__((ext_vector_type(4))) float v4f;   // MFMA C/D frag

__device__ __forceinline__ uint16_t f2bf(float x){
  uint32_t u = __float_as_uint(x);
  return (uint16_t)((u + 0x7FFFu + ((u >> 16) & 1u)) >> 16);  // RNE
}
__device__ __forceinline__ uint32_t pk2(float a, float b){
  return (uint32_t)f2bf(a) | ((uint32_t)f2bf(b) << 16);
}

// async global->LDS, 16B per lane. LDS dest is wave-uniform-base + lane*16 (linear).
__device__ __forceinline__ void gl16(const uint16_t* g, uint16_t* l){
  __builtin_amdgcn_global_load_lds((const __attribute__((address_space(1))) void*)g,
                                   (__attribute__((address_space(3))) void*)l, 16, 0, 0);
}

// ---------- fused prep: one launch, block-range dispatch ----------
// [0,3136)      tdec : dec f32 NCHW -> decT bf16 [b][pos][ci] (128x128 tile, rot-swizzle)
// [3136,4160)   wpe2 : pe_w -> [co][pix*512+ci] bf16 via LDS transpose (contiguous reads)
// [4160,4288)   cvt mcw ; [4288,4416) cvt rcw
// [4416,4544)   tcvt wq ; [4544,4736) tcvt wk ; [4736,4928) tcvt wv ; [4928,5056) tcvt wo
// [5056,5728)   transb  ; [5728,5730) scales
__device__ __forceinline__ void prep_cvt(const float* s, uint16_t* d, int id, int n8){
  if (id >= n8) return;
  const float4* sp = (const float4*)(s + (size_t)id * 8);
  float4 f0 = sp[0], f1 = sp[1];
  uint4 u; u.x = pk2(f0.x, f0.y); u.y = pk2(f0.z, f0.w);
  u.z = pk2(f1.x, f1.y); u.w = pk2(f1.z, f1.w);
  *(uint4*)(d + (size_t)id * 8) = u;
}
__device__ __forceinline__ void prep_tcvt(const float* s, uint16_t* d, int id, int R, int C){
  int r8 = R >> 3;
  if (id >= C * r8) return;
  int c = id / r8, r0 = (id - c * r8) * 8;
  float v[8];
  #pragma unroll
  for (int e = 0; e < 8; e++) v[e] = s[(size_t)(r0 + e) * C + c];
  uint4 u; u.x = pk2(v[0], v[1]); u.y = pk2(v[2], v[3]);
  u.z = pk2(v[4], v[5]); u.w = pk2(v[6], v[7]);
  *(uint4*)(d + (size_t)c * R + r0) = u;
}

__global__ void __launch_bounds__(256) dra_prep(
    const float* __restrict__ dec, uint16_t* __restrict__ decT,
    const float* __restrict__ pw, uint16_t* __restrict__ w2,
    const float* __restrict__ mc_w, uint16_t* __restrict__ mcw,
    const float* __restrict__ rc_w, uint16_t* __restrict__ rcw,
    const float* __restrict__ wq, uint16_t* __restrict__ wqT,
    const float* __restrict__ wk, uint16_t* __restrict__ wkT,
    const float* __restrict__ wv, uint16_t* __restrict__ wvT,
    const float* __restrict__ wo, uint16_t* __restrict__ woT,
    const float* __restrict__ tr, uint16_t* __restrict__ transb,
    const float* __restrict__ mcb, const float* __restrict__ g1, const float* __restrict__ b1,
    const float* __restrict__ m1, const float* __restrict__ v1,
    const float* __restrict__ rcb, const float* __restrict__ g2, const float* __restrict__ b2,
    const float* __restrict__ m2, const float* __restrict__ v2,
    float* __restrict__ s1, float* __restrict__ o1, float* __restrict__ s2, float* __restrict__ o2)
{
  __shared__ uint16_t lt[128 * 128];   // 32KB; tdec: [128 pos][128 ci]; wpe2: [64 pix][256 cl]
  int B = blockIdx.x, t = threadIdx.x;

  if (B < 3136){                                    // ---- tdec (128 pos x 128 ci tile) ----
    int pos0 = (B % 98) * 128;
    int ci0  = ((B / 98) & 3) * 128;
    int b    = B / 392;
    // write: element (p,c) -> lt[p*128 + (((c>>3)+(p>>2))&15)*8 + (c&7)]
    #pragma unroll
    for (int i = 0; i < 16; i++){
      int u = t + i * 256;
      int ci_l = u >> 5, p4 = (u & 31) * 4;
      const float4 f = *(const float4*)(dec + ((size_t)(b * 512 + ci0 + ci_l)) * 12544 + pos0 + p4);
      float v[4] = {f.x, f.y, f.z, f.w};
      #pragma unroll
      for (int j = 0; j < 4; j++){
        int p = p4 + j;
        int bp = ((ci_l >> 3) + (p >> 2)) & 15;
        lt[p * 128 + bp * 8 + (ci_l & 7)] = f2bf(v[j]);
      }
    }
    __syncthreads();
    #pragma unroll
    for (int i = 0; i < 8; i++){
      int idx = t + i * 256;
      int p_l = idx >> 4, u = idx & 15;
      int bp = (u + (p_l >> 2)) & 15;
      uint4 v = *(const uint4*)&lt[p_l * 128 + bp * 8];
      *(uint4*)(decT + ((size_t)b * 12544 + pos0 + p_l) * 512 + ci0 + u * 8) = v;
    }
  } else if (B < 4160){                             // ---- wpe2 via LDS transpose ----
    int blk = B - 3136;                             // co*2 + cihalf
    int co = blk >> 1, ch = blk & 1;
    const float* src = pw + (size_t)co * 32768 + ch * 16384;   // 64KB contiguous
    // f = cl*64 + pix  (ci = ch*256+cl);  write lt[pix][cl] with bp=((cl>>3)+pix)&31
    #pragma unroll
    for (int i = 0; i < 16; i++){
      int id4 = (t + i * 256) * 4;
      const float4 f = *(const float4*)(src + id4);
      int cl = id4 >> 6, pix0 = id4 & 63;
      float v[4] = {f.x, f.y, f.z, f.w};
      #pragma unroll
      for (int j = 0; j < 4; j++){
        int pix = pix0 + j;
        int bp = ((cl >> 3) + pix) & 31;
        lt[pix * 256 + bp * 8 + (cl & 7)] = f2bf(v[j]);
      }
    }
    __syncthreads();
    // read row pix: logical block u at physical (u+pix)&31; emit 512B-contiguous rows
    #pragma unroll
    for (int i = 0; i < 8; i++){
      int unit = t + i * 256;
      int pix = unit >> 5, u = unit & 31;
      int bp = (u + pix) & 31;
      uint4 v = *(const uint4*)&lt[pix * 256 + bp * 8];
      *(uint4*)(w2 + (size_t)co * 32768 + pix * 512 + ch * 256 + u * 8) = v;
    }
  } else if (B < 4288){ prep_cvt(mc_w, mcw, (B - 4160) * 256 + t, 32768); }
  else if (B < 4416){ prep_cvt(rc_w, rcw, (B - 4288) * 256 + t, 32768); }
  else if (B < 4544){ prep_tcvt(wq, wqT, (B - 4416) * 256 + t, 512, 512); }
  else if (B < 4736){ prep_tcvt(wk, wkT, (B - 4544) * 256 + t, 768, 512); }
  else if (B < 4928){ prep_tcvt(wv, wvT, (B - 4736) * 256 + t, 768, 512); }
  else if (B < 5056){ prep_tcvt(wo, woT, (B - 4928) * 256 + t, 512, 512); }
  else if (B < 5728){                               // ---- transb ----
    int id = (B - 5056) * 256 + t;
    if (id < 1792 * 96){
      int n = id / 96, e0 = (id - n * 96) * 8;
      int b = n / 224, nl = n - b * 224;
      uint4 u = {0u,0u,0u,0u};
      if (nl < 196){
        const float* sp = tr + ((size_t)(b * 196 + nl)) * 768 + e0;
        u.x = pk2(sp[0], sp[1]); u.y = pk2(sp[2], sp[3]);
        u.z = pk2(sp[4], sp[5]); u.w = pk2(sp[6], sp[7]);
      }
      *(uint4*)(transb + (size_t)n * 768 + e0) = u;
    }
  } else {                                          // ---- scales ----
    int i = (B - 5728) * 256 + t;
    if (i < 512){
      float sc1 = g1[i] / sqrtf(v1[i] + 1e-3f);
      s1[i] = sc1; o1[i] = (mcb[i] - m1[i]) * sc1 + b1[i];
      float sc2 = g2[i] / sqrtf(v2[i] + 1e-3f);
      s2[i] = sc2; o2[i] = (rcb[i] - m2[i]) * sc2 + b2[i];
    }
  }
}

// ---------- K1: patch-embed as split-K GEMM with partial buffers (round-5 best) ----------
__global__ void __launch_bounds__(256, 4) dra_k1(const uint16_t* __restrict__ decT,
    const uint16_t* __restrict__ wpe2, float* __restrict__ part)
{
  __shared__ uint16_t lA[128 * 32];
  __shared__ uint16_t lB[128 * 32];
  int t = threadIdx.x;
  int L = blockIdx.x;
  int x = L & 7, n = L >> 3;           // n in [0,112)
  int shi = n / 56, rem = n - shi * 56;
  int tok_t = rem >> 2, co_t = rem & 3;
  int s    = shi * 8 + x;              // split 0..15 pinned to xcd x
  int bco  = co_t * 128;
  int tok0 = tok_t * 128;
  int lane = t & 63, w = t >> 6;
  int wm = w >> 1, wn = w & 1;
  int lr = lane & 15, lg = lane >> 4;

  const uint16_t* aB[2]; const uint16_t* bB[2]; int uu[2];
  #pragma unroll
  for (int i = 0; i < 2; i++){
    int u = t + i * 256; uu[i] = u;
    int row = u >> 2, h = u & 3;
    int token = tok0 + row;
    int b = token / 224, tl = token - b * 224;
    if (tl > 195) tl = 195;                       // clamp pad tokens (finite garbage, unused later)
    int py = tl / 14, px = tl - py * 14;
    aB[i] = decT + ((size_t)b * 12544 + py * 896 + px * 8) * 512 + h * 8;
    bB[i] = wpe2 + (size_t)(bco + row) * 32768 + h * 8;
  }

  const v4f vzero = {0.f,0.f,0.f,0.f};
  v4f acc[4][4];
  #pragma unroll
  for (int i = 0; i < 4; i++)
    #pragma unroll
    for (int j = 0; j < 4; j++) acc[i][j] = vzero;

  for (int pix = s * 4; pix < s * 4 + 4; ++pix){
    int ky = pix >> 3, kx = pix & 7;
    int poff = (ky * 112 + kx) * 512;
    int k0p  = pix * 512;
    for (int ci0 = 0; ci0 < 512; ci0 += 32){
      gl16(aB[0] + poff + ci0, &lA[uu[0] * 8]);
      gl16(aB[1] + poff + ci0, &lA[uu[1] * 8]);
      gl16(bB[0] + k0p + ci0,  &lB[uu[0] * 8]);
      gl16(bB[1] + k0p + ci0,  &lB[uu[1] * 8]);
      __syncthreads();
      v8s av[4], bv[4];
      #pragma unroll
      for (int mf = 0; mf < 4; mf++) av[mf] = *(const v8s*)&lA[(wm*64 + mf*16 + lr) * 32 + lg * 8];
      #pragma unroll
      for (int nf = 0; nf < 4; nf++) bv[nf] = *(const v8s*)&lB[(wn*64 + nf*16 + lr) * 32 + lg * 8];
      #pragma unroll
      for (int mf = 0; mf < 4; mf++)
        #pragma unroll
        for (int nf = 0; nf < 4; nf++)
          acc[mf][nf] = __builtin_amdgcn_mfma_f32_16x16x32_bf16(av[mf], bv[nf], acc[mf][nf], 0, 0, 0);
      __syncthreads();
    }
  }
  float* pd = part + (size_t)s * 917504;
  #pragma unroll
  for (int mf = 0; mf < 4; mf++){
    #pragma unroll
    for (int nf = 0; nf < 4; nf++){
      int tokg = tok0 + wm*64 + mf*16 + lg*4;
      int cog  = bco  + wn*64 + nf*16 + lr;
      #pragma unroll
      for (int r = 0; r < 4; r++)
        pd[(size_t)(tokg + r) * 512 + cog] = acc[mf][nf][r];
    }
  }
}

// reduce 16 split partials + bias -> dlb bf16 [1792][512]
__global__ void __launch_bounds__(256) dra_red(const float* __restrict__ part,
    const float* __restrict__ peb, uint16_t* __restrict__ dlb){
  int id = blockIdx.x * 256 + threadIdx.x;
  if (id >= 114688) return;
  int tok = id >> 6, c8 = (id & 63) * 8;
  float a0=0,a1=0,a2=0,a3=0,a4=0,a5=0,a6=0,a7=0;
  #pragma unroll
  for (int s = 0; s < 16; s++){
    const float* p = part + (size_t)s * 917504 + (size_t)tok * 512 + c8;
    float4 x = *(const float4*)p, y = *(const float4*)(p + 4);
    a0 += x.x; a1 += x.y; a2 += x.z; a3 += x.w;
    a4 += y.x; a5 += y.y; a6 += y.z; a7 += y.w;
  }
  const float4 b0 = *(const float4*)(peb + c8), b1 = *(const float4*)(peb + c8 + 4);
  uint4 o; o.x = pk2(a0 + b0.x, a1 + b0.y); o.y = pk2(a2 + b0.z, a3 + b0.w);
  o.z = pk2(a4 + b1.x, a5 + b1.y); o.w = pk2(a6 + b1.z, a7 + b1.w);
  *(uint4*)(dlb + (size_t)tok * 512 + c8) = o;
}

// ---------- generic NT GEMM (attention chain): D[m][n] = sum_k A[m][k]*B[n][k] ----------
// BM = MREP*32, BN=64, BK=32, 256 threads (2x2 waves). Staging via global_load_lds with
// source-chunk swizzle c^((row>>1)&3): even rows cycle all 4 slots -> 2 lanes/bank (free).
template<int MREP>
__global__ void __launch_bounds__(256, 2) dra_gemm(
    const uint16_t* __restrict__ A, const uint16_t* __restrict__ Bn, void* __restrict__ Dv,
    int M, int N, int K, int lda, int ldb, int ldd,
    long long sAz, long long sBz, long long sDz,
    int epi, const float* __restrict__ svec, const float* __restrict__ ovec)
{
  constexpr int BM = MREP * 32;
  __shared__ uint16_t lA[BM * 32];
  __shared__ uint16_t lB[64 * 32];
  int t = threadIdx.x, z = blockIdx.z;
  int bm = blockIdx.x * BM, bn = blockIdx.y * 64;
  const uint16_t* Az = A + (size_t)z * sAz;
  const uint16_t* Bz = Bn + (size_t)z * sBz;
  int lane = t & 63, w = t >> 6;
  int wm = w >> 1, wn = w & 1;
  int lr = lane & 15, lg = lane >> 4;

  const uint16_t* aSrc[MREP/2]; int uuA[MREP/2];
  #pragma unroll
  for (int i = 0; i < MREP/2; i++){
    int u = t + i * 256; uuA[i] = u;
    int row = u >> 2, c = u & 3;
    int cs = c ^ ((row >> 1) & 3);
    int rg = bm + row; if (rg >= M) rg = M - 1;
    aSrc[i] = Az + (size_t)rg * lda + cs * 8;
  }
  const uint16_t* bSrc;
  {
    int row = t >> 2, c = t & 3;
    int cs = c ^ ((row >> 1) & 3);
    bSrc = Bz + (size_t)(bn + row) * ldb + cs * 8;
  }

  int aoff[MREP], boff[2];
  #pragma unroll
  for (int mf = 0; mf < MREP; mf++){
    int R = wm*(MREP*16) + mf*16 + lr;
    aoff[mf] = R * 32 + (lg ^ ((R >> 1) & 3)) * 8;
  }
  #pragma unroll
  for (int nf = 0; nf < 2; nf++){
    int R = wn*32 + nf*16 + lr;
    boff[nf] = R * 32 + (lg ^ ((R >> 1) & 3)) * 8;
  }

  const v4f vzero = {0.f, 0.f, 0.f, 0.f};
  v4f acc[MREP][2];
  #pragma unroll
  for (int i = 0; i < MREP; i++){ acc[i][0] = vzero; acc[i][1] = vzero; }

  for (int k0 = 0; k0 < K; k0 += 32){
    #pragma unroll
    for (int i = 0; i < MREP/2; i++)
      gl16(aSrc[i] + k0, &lA[uuA[i] * 8]);
    gl16(bSrc + k0, &lB[t * 8]);
    __syncthreads();
    v8s av[MREP], bv[2];
    #pragma unroll
    for (int mf = 0; mf < MREP; mf++) av[mf] = *(const v8s*)&lA[aoff[mf]];
    #pragma unroll
    for (int nf = 0; nf < 2; nf++)    bv[nf] = *(const v8s*)&lB[boff[nf]];
    #pragma unroll
    for (int mf = 0; mf < MREP; mf++)
      #pragma unroll
      for (int nf = 0; nf < 2; nf++)
        acc[mf][nf] = __builtin_amdgcn_mfma_f32_16x16x32_bf16(av[mf], bv[nf], acc[mf][nf], 0, 0, 0);
    __syncthreads();
  }

  #pragma unroll
  for (int mf = 0; mf < MREP; mf++){
    #pragma unroll
    for (int nf = 0; nf < 2; nf++){
      int mg0 = bm + wm*(MREP*16) + mf*16 + lg*4;
      int ng  = bn + wn*32 + nf*16 + lr;
      #pragma unroll
      for (int r = 0; r < 4; r++){
        int mg = mg0 + r;
        if (mg < M){
          float val = acc[mf][nf][r];
          size_t di = (size_t)z * sDz + (size_t)mg * ldd + ng;
          if (epi == 0)      ((float*)Dv)[di] = val;
          else if (epi == 1) ((uint16_t*)Dv)[di] = f2bf(val);
          else ((float*)Dv)[di] = fmaxf(val * svec[mg] + ovec[mg], 0.f);
        }
      }
    }
  }
}

// ---------- InstanceNorm stats: two-stage deterministic tree reduction ----------
__global__ void __launch_bounds__(256) dra_stats1(const float* __restrict__ sim,
                                                  double* __restrict__ ps){
  __shared__ double d1[256], d2[256];
  int b = blockIdx.y, blk = blockIdx.x, t = threadIdx.x;
  const float* s = sim + (size_t)b * 262144 + (size_t)blk * 2048 + t * 8;
  float4 x = *(const float4*)s, y = *(const float4*)(s + 4);
  double p1 = (double)x.x + x.y + x.z + x.w + y.x + y.y + y.z + y.w;
  double p2 = (double)x.x*x.x + (double)x.y*x.y + (double)x.z*x.z + (double)x.w*x.w
            + (double)y.x*y.x + (double)y.y*y.y + (double)y.z*y.z + (double)y.w*y.w;
  d1[t] = p1; d2[t] = p2;
  __syncthreads();
  for (int o = 128; o > 0; o >>= 1){
    if (t < o){ d1[t] += d1[t + o]; d2[t] += d2[t + o]; }
    __syncthreads();
  }
  if (t == 0){
    ps[(b * 128 + blk) * 2 + 0] = d1[0];
    ps[(b * 128 + blk) * 2 + 1] = d2[0];
  }
}

__global__ void __launch_bounds__(128) dra_stats2(const double* __restrict__ ps,
    const float* __restrict__ psig, const float* __restrict__ psib, float* __restrict__ ac){
  __shared__ double d1[128], d2[128];
  int b = blockIdx.x, t = threadIdx.x;
  d1[t] = ps[(b * 128 + t) * 2 + 0];
  d2[t] = ps[(b * 128 + t) * 2 + 1];
  __syncthreads();
  for (int o = 64; o > 0; o >>= 1){
    if (t < o){ d1[t] += d1[t + o]; d2[t] += d2[t + o]; }
    __syncthreads();
  }
  if (t == 0){
    double mean = d1[0] * (1.0 / 262144.0);
    double var  = d2[0] * (1.0 / 262144.0) - mean * mean;
    float a = psig[0] / (float)sqrt(var + 1e-3);
    ac[b * 2 + 0] = a;
    ac[b * 2 + 1] = psib[0] - (float)mean * a;
  }
}

// ---------- row softmax: P[b][s][t] bf16 ----------
__global__ void __launch_bounds__(256) dra_soft(const float* __restrict__ sim,
    const float* __restrict__ ac, uint16_t* __restrict__ P){
  int srow = blockIdx.x, b = blockIdx.y, t = threadIdx.x;
  const float* row = sim + (size_t)b * 262144 + (size_t)srow * 512;
  float a = ac[b * 2], c = ac[b * 2 + 1];
  float v0 = row[t] * a + c, v1 = row[t + 256] * a + c;
  __shared__ float red[256];
  red[t] = fmaxf(v0, v1);
  __syncthreads();
  for (int o = 128; o > 0; o >>= 1){
    if (t < o) red[t] = fmaxf(red[t], red[t + o]);
    __syncthreads();
  }
  float m = red[0];
  __syncthreads();
  float e0 = __expf(v0 - m), e1 = __expf(v1 - m);
  red[t] = e0 + e1;
  __syncthreads();
  for (int o = 128; o > 0; o >>= 1){
    if (t < o) red[t] += red[t + o];
    __syncthreads();
  }
  float inv = 1.f / red[0];
  uint16_t* pr = P + (size_t)b * 262144 + (size_t)srow * 512;
  pr[t] = f2bf(e0 * inv); pr[t + 256] = f2bf(e1 * inv);
}

// ---------- K3: mask conv + BN1 + ReLU, fused x recon-upsample -> out (round-5 best) ----------
__global__ void __launch_bounds__(256, 4) dra_k3(const uint16_t* __restrict__ decT,
    const uint16_t* __restrict__ mcw, const float* __restrict__ s1,
    const float* __restrict__ o1, const float* __restrict__ recon,
    float* __restrict__ outp)
{
  __shared__ uint16_t lA[128 * 32];
  __shared__ uint16_t lB[128 * 32];
  int t = threadIdx.x;
  int L = blockIdx.x;
  int x = L & 7, n = L >> 3;          // n in [0,392)
  int co_t = n & 3, pg = n >> 2;      // pg in [0,98)
  int p = pg * 8 + x;                 // pos-tile x batch, pinned to xcd x
  int bz = p / 98, pt = p - bz * 98;
  int bco  = co_t * 128;
  int pos0 = pt * 128;
  int lane = t & 63, w = t >> 6;
  int wm = w >> 1, wn = w & 1;
  int lr = lane & 15, lg = lane >> 4;

  const uint16_t* aB[2]; const uint16_t* bB[2]; int uu[2];
  #pragma unroll
  for (int i = 0; i < 2; i++){
    int u = t + i * 256; uu[i] = u;
    int row = u >> 2, h = u & 3;
    aB[i] = mcw  + (size_t)(bco + row) * 512 + h * 8;
    bB[i] = decT + ((size_t)bz * 12544 + pos0 + row) * 512 + h * 8;
  }

  const v4f vzero = {0.f,0.f,0.f,0.f};
  v4f acc[4][4];
  #pragma unroll
  for (int i = 0; i < 4; i++)
    #pragma unroll
    for (int j = 0; j < 4; j++) acc[i][j] = vzero;

  for (int k0 = 0; k0 < 512; k0 += 32){
    gl16(aB[0] + k0, &lA[uu[0] * 8]);
    gl16(aB[1] + k0, &lA[uu[1] * 8]);
    gl16(bB[0] + k0, &lB[uu[0] * 8]);
    gl16(bB[1] + k0, &lB[uu[1] * 8]);
    __syncthreads();
    v8s av[4], bv[4];
    #pragma unroll
    for (int mf = 0; mf < 4; mf++) av[mf] = *(const v8s*)&lA[(wm*64 + mf*16 + lr) * 32 + lg * 8];
    #pragma unroll
    for (int nf = 0; nf < 4; nf++) bv[nf] = *(const v8s*)&lB[(wn*64 + nf*16 + lr) * 32 + lg * 8];
    #pragma unroll
    for (int mf = 0; mf < 4; mf++)
      #pragma unroll
      for (int nf = 0; nf < 4; nf++)
        acc[mf][nf] = __builtin_amdgcn_mfma_f32_16x16x32_bf16(av[mf], bv[nf], acc[mf][nf], 0, 0, 0);
    __syncthreads();
  }

  #pragma unroll
  for (int mf = 0; mf < 4; mf++){
    #pragma unroll
    for (int r = 0; r < 4; r++){
      int co = bco + wm*64 + mf*16 + lg*4 + r;
      float sc = s1[co], of = o1[co];
      const float* rrow = recon + (size_t)co * 1792 + bz * 224;
      #pragma unroll
      for (int nf = 0; nf < 4; nf++){
        int pos = pos0 + wn*64 + nf*16 + lr;
        int h = pos / 112, wd = pos - h * 112;
        int pcol = (h >> 3) * 14 + (wd >> 3);
        float mask = fmaxf(acc[mf][nf][r] * sc + of, 0.f);
        outp[((size_t)(bz * 512 + co)) * 12544 + pos] = mask * rrow[pcol];
      }
    }
  }
}

// ---------- launch ----------
extern "C" void kernel_launch(void* const* d_in, const int* in_sizes, int n_in,
                              void* d_out, int out_size, void* d_ws, size_t ws_size,
                              hipStream_t stream) {
  (void)in_sizes; (void)n_in; (void)out_size; (void)ws_size;
  const float* dec   = (const float*)d_in[0];
  const float* trans = (const float*)d_in[1];
  const float* pe_w  = (const float*)d_in[2];
  const float* pe_b  = (const float*)d_in[3];
  const float* mc_w  = (const float*)d_in[4];
  const float* mc_b  = (const float*)d_in[5];
  const float* bn1g  = (const float*)d_in[6];
  const float* bn1b  = (const float*)d_in[7];
  const float* bn1m  = (const float*)d_in[8];
  const float* bn1v  = (const float*)d_in[9];
  const float* wq    = (const float*)d_in[10];
  const float* wk    = (const float*)d_in[11];
  const float* wv    = (const float*)d_in[12];
  const float* wo    = (const float*)d_in[13];
  const float* psig  = (const float*)d_in[14];
  const float* psib  = (const float*)d_in[15];
  const float* rc_w  = (const float*)d_in[16];
  const float* rc_b  = (const float*)d_in[17];
  const float* bn2g  = (const float*)d_in[18];
  const float* bn2b  = (const float*)d_in[19];
  const float* bn2m  = (const float*)d_in[20];
  const float* bn2v  = (const float*)d_in[21];

  char* p = (char*)d_ws;
  auto take = [&](size_t bytes) -> void* {
    void* r = (void*)p; p += (bytes + 255) & ~(size_t)255; return r;
  };
  uint16_t* decT   = (uint16_t*)take((size_t)8 * 12544 * 512 * 2);   // 102.8 MB
  uint16_t* wpe2   = (uint16_t*)take((size_t)512 * 32768 * 2);       // 33.5 MB
  uint16_t* mcw    = (uint16_t*)take((size_t)512 * 512 * 2);
  uint16_t* rcw    = (uint16_t*)take((size_t)512 * 512 * 2);
  uint16_t* wqT    = (uint16_t*)take((size_t)512 * 512 * 2);
  uint16_t* woT    = (uint16_t*)take((size_t)512 * 512 * 2);
  uint16_t* wkT    = (uint16_t*)take((size_t)512 * 768 * 2);
  uint16_t* wvT    = (uint16_t*)take((size_t)512 * 768 * 2);
  uint16_t* transb = (uint16_t*)take((size_t)1792 * 768 * 2);
  float*    s1v    = (float*)take(512 * 4);
  float*    o1v    = (float*)take(512 * 4);
  float*    s2v    = (float*)take(512 * 4);
  float*    o2v    = (float*)take(512 * 4);
  uint16_t* dlb    = (uint16_t*)take((size_t)1792 * 512 * 2);
  uint16_t* Qt     = (uint16_t*)take((size_t)512 * 1792 * 2);
  uint16_t* Kt     = (uint16_t*)take((size_t)512 * 1792 * 2);
  uint16_t* Vb     = (uint16_t*)take((size_t)1792 * 512 * 2);
  float*    ac     = (float*)take(256);
  double*   ps     = (double*)take((size_t)8 * 128 * 2 * 8);         // 16 KB stats partials
  float*    part   = (float*)take((size_t)16 * 1792 * 512 * 4);      // 58.7 MB
  // alias attention temps inside part (consumed by dra_red before these are written)
  float*    simb   = part;                                            // 8.39 MB
  uint16_t* P      = (uint16_t*)(part + 2097152);                     // 4.19 MB
  uint16_t* outb   = P + 2097152;                                     // 1.84 MB
  uint16_t* out2   = outb + 917504;                                   // 1.84 MB
  float*    recon  = (float*)(out2 + 917504);                         // 3.67 MB

  // fused prep (tdec 128x128 + wpe2-transpose + cvt x2 + tcvt x4 + transb + scales)
  dra_prep<<<5730, 256, 0, stream>>>(dec, decT, pe_w, wpe2, mc_w, mcw, rc_w, rcw,
      wq, wqT, wk, wkT, wv, wvT, wo, woT, trans, transb,
      mc_b, bn1g, bn1b, bn1m, bn1v, rc_b, bn2g, bn2b, bn2m, bn2v,
      s1v, o1v, s2v, o2v);

  // patch embedding: split-K partials + reduce (-> dlb bf16)
  dra_k1<<<896, 256, 0, stream>>>(decT, wpe2, part);
  dra_red<<<448, 256, 0, stream>>>(part, pe_b, dlb);

  // Qt[s][n] ; Kt[t][n] ; Vb[n][t]
  dra_gemm<2><<<dim3(8, 28, 1), 256, 0, stream>>>(wqT, dlb, Qt, 512, 1792, 512,
      512, 512, 1792, 0, 0, 0, 1, nullptr, nullptr);
  dra_gemm<2><<<dim3(8, 28, 1), 256, 0, stream>>>(wkT, transb, Kt, 512, 1792, 768,
      768, 768, 1792, 0, 0, 0, 1, nullptr, nullptr);
  dra_gemm<2><<<dim3(28, 8, 1), 256, 0, stream>>>(transb, wvT, Vb, 1792, 512, 768,
      768, 768, 512, 0, 0, 0, 1, nullptr, nullptr);

  // sim = Qt x Kt over padded tokens (zeros in pad cols of Kt)
  dra_gemm<2><<<dim3(8, 8, 8), 256, 0, stream>>>(Qt, Kt, simb, 512, 512, 224,
      1792, 1792, 512, 224, 224, 262144, 0, nullptr, nullptr);
  dra_stats1<<<dim3(128, 8), 256, 0, stream>>>(simb, ps);
  dra_stats2<<<8, 128, 0, stream>>>(ps, psig, psib, ac);
  dra_soft<<<dim3(512, 8), 256, 0, stream>>>(simb, ac, P);

  // out = P x V ; out2 = out x wo ; recon = relu(bn2(rc(out2)))
  dra_gemm<2><<<dim3(4, 8, 8), 256, 0, stream>>>(Vb, P, outb, 224, 512, 512,
      512, 512, 512, 114688, 262144, 114688, 1, nullptr, nullptr);
  dra_gemm<2><<<dim3(28, 8, 1), 256, 0, stream>>>(outb, woT, out2, 1792, 512, 512,
      512, 512, 512, 0, 0, 0, 1, nullptr, nullptr);
  dra_gemm<2><<<dim3(8, 28, 1), 256, 0, stream>>>(rcw, out2, recon, 512, 1792, 512,
      512, 512, 1792, 0, 0, 0, 2, s2v, o2v);

  // mask conv + BN1 + ReLU, x upsampled recon -> final output
  dra_k3<<<3136, 256, 0, stream>>>(decT, mcw, s1v, o1v, recon, (float*)d_out);
}

// Round 17
// 384.961 us; speedup vs baseline: 1.0427x; 1.0020x over previous
//
#include <hip/hip_runtime.h>
#include <stdint.h>

// ---------- types & helpers ----------
typedef __attribute__((ext_vector_type(8))) short v8s;   // 8 x bf16 (4 VGPRs)
typedef __attribute__((ext_vector_type(4))) float v4f;   // MFMA C/D frag

__device__ __forceinline__ uint16_t f2bf(float x){
  uint32_t u = __float_as_uint(x);
  return (uint16_t)((u + 0x7FFFu + ((u >> 16) & 1u)) >> 16);  // RNE
}
__device__ __forceinline__ uint32_t pk2(float a, float b){
  return (uint32_t)f2bf(a) | ((uint32_t)f2bf(b) << 16);
}

// async global->LDS, 16B per lane. LDS dest is wave-uniform-base + lane*16 (linear).
__device__ __forceinline__ void gl16(const uint16_t* g, uint16_t* l){
  __builtin_amdgcn_global_load_lds((const __attribute__((address_space(1))) void*)g,
                                   (__attribute__((address_space(3))) void*)l, 16, 0, 0);
}

// ---------- fused prep: one launch, block-range dispatch ----------
// [0,3136)      tdec : dec f32 NCHW -> decT bf16 [b][pos][ci] (128x128 tile, rot-swizzle)
// [3136,4160)   wpe2 : pe_w -> [co][pix*512+ci] bf16 via LDS transpose (contiguous reads)
// [4160,4288)   cvt mcw ; [4288,4416) cvt rcw
// [4416,4544)   tcvt wq ; [4544,4736) tcvt wk ; [4736,4928) tcvt wv ; [4928,5056) tcvt wo
// [5056,5728)   transb  ; [5728,5730) scales
__device__ __forceinline__ void prep_cvt(const float* s, uint16_t* d, int id, int n8){
  if (id >= n8) return;
  const float4* sp = (const float4*)(s + (size_t)id * 8);
  float4 f0 = sp[0], f1 = sp[1];
  uint4 u; u.x = pk2(f0.x, f0.y); u.y = pk2(f0.z, f0.w);
  u.z = pk2(f1.x, f1.y); u.w = pk2(f1.z, f1.w);
  *(uint4*)(d + (size_t)id * 8) = u;
}
__device__ __forceinline__ void prep_tcvt(const float* s, uint16_t* d, int id, int R, int C){
  int r8 = R >> 3;
  if (id >= C * r8) return;
  int c = id / r8, r0 = (id - c * r8) * 8;
  float v[8];
  #pragma unroll
  for (int e = 0; e < 8; e++) v[e] = s[(size_t)(r0 + e) * C + c];
  uint4 u; u.x = pk2(v[0], v[1]); u.y = pk2(v[2], v[3]);
  u.z = pk2(v[4], v[5]); u.w = pk2(v[6], v[7]);
  *(uint4*)(d + (size_t)c * R + r0) = u;
}

__global__ void __launch_bounds__(256) dra_prep(
    const float* __restrict__ dec, uint16_t* __restrict__ decT,
    const float* __restrict__ pw, uint16_t* __restrict__ w2,
    const float* __restrict__ mc_w, uint16_t* __restrict__ mcw,
    const float* __restrict__ rc_w, uint16_t* __restrict__ rcw,
    const float* __restrict__ wq, uint16_t* __restrict__ wqT,
    const float* __restrict__ wk, uint16_t* __restrict__ wkT,
    const float* __restrict__ wv, uint16_t* __restrict__ wvT,
    const float* __restrict__ wo, uint16_t* __restrict__ woT,
    const float* __restrict__ tr, uint16_t* __restrict__ transb,
    const float* __restrict__ mcb, const float* __restrict__ g1, const float* __restrict__ b1,
    const float* __restrict__ m1, const float* __restrict__ v1,
    const float* __restrict__ rcb, const float* __restrict__ g2, const float* __restrict__ b2,
    const float* __restrict__ m2, const float* __restrict__ v2,
    float* __restrict__ s1, float* __restrict__ o1, float* __restrict__ s2, float* __restrict__ o2)
{
  __shared__ uint16_t lt[128 * 128];   // 32KB; tdec: [128 pos][128 ci]; wpe2: [64 pix][256 cl]
  int B = blockIdx.x, t = threadIdx.x;

  if (B < 3136){                                    // ---- tdec (128 pos x 128 ci tile) ----
    int pos0 = (B % 98) * 128;
    int ci0  = ((B / 98) & 3) * 128;
    int b    = B / 392;
    // write: element (p,c) -> lt[p*128 + (((c>>3)+(p>>2))&15)*8 + (c&7)]
    #pragma unroll
    for (int i = 0; i < 16; i++){
      int u = t + i * 256;
      int ci_l = u >> 5, p4 = (u & 31) * 4;
      const float4 f = *(const float4*)(dec + ((size_t)(b * 512 + ci0 + ci_l)) * 12544 + pos0 + p4);
      float v[4] = {f.x, f.y, f.z, f.w};
      #pragma unroll
      for (int j = 0; j < 4; j++){
        int p = p4 + j;
        int bp = ((ci_l >> 3) + (p >> 2)) & 15;
        lt[p * 128 + bp * 8 + (ci_l & 7)] = f2bf(v[j]);
      }
    }
    __syncthreads();
    #pragma unroll
    for (int i = 0; i < 8; i++){
      int idx = t + i * 256;
      int p_l = idx >> 4, u = idx & 15;
      int bp = (u + (p_l >> 2)) & 15;
      uint4 v = *(const uint4*)&lt[p_l * 128 + bp * 8];
      *(uint4*)(decT + ((size_t)b * 12544 + pos0 + p_l) * 512 + ci0 + u * 8) = v;
    }
  } else if (B < 4160){                             // ---- wpe2 via LDS transpose ----
    int blk = B - 3136;                             // co*2 + cihalf
    int co = blk >> 1, ch = blk & 1;
    const float* src = pw + (size_t)co * 32768 + ch * 16384;   // 64KB contiguous
    #pragma unroll
    for (int i = 0; i < 16; i++){
      int id4 = (t + i * 256) * 4;
      const float4 f = *(const float4*)(src + id4);
      int cl = id4 >> 6, pix0 = id4 & 63;
      float v[4] = {f.x, f.y, f.z, f.w};
      #pragma unroll
      for (int j = 0; j < 4; j++){
        int pix = pix0 + j;
        int bp = ((cl >> 3) + pix) & 31;
        lt[pix * 256 + bp * 8 + (cl & 7)] = f2bf(v[j]);
      }
    }
    __syncthreads();
    #pragma unroll
    for (int i = 0; i < 8; i++){
      int unit = t + i * 256;
      int pix = unit >> 5, u = unit & 31;
      int bp = (u + pix) & 31;
      uint4 v = *(const uint4*)&lt[pix * 256 + bp * 8];
      *(uint4*)(w2 + (size_t)co * 32768 + pix * 512 + ch * 256 + u * 8) = v;
    }
  } else if (B < 4288){ prep_cvt(mc_w, mcw, (B - 4160) * 256 + t, 32768); }
  else if (B < 4416){ prep_cvt(rc_w, rcw, (B - 4288) * 256 + t, 32768); }
  else if (B < 4544){ prep_tcvt(wq, wqT, (B - 4416) * 256 + t, 512, 512); }
  else if (B < 4736){ prep_tcvt(wk, wkT, (B - 4544) * 256 + t, 768, 512); }
  else if (B < 4928){ prep_tcvt(wv, wvT, (B - 4736) * 256 + t, 768, 512); }
  else if (B < 5056){ prep_tcvt(wo, woT, (B - 4928) * 256 + t, 512, 512); }
  else if (B < 5728){                               // ---- transb ----
    int id = (B - 5056) * 256 + t;
    if (id < 1792 * 96){
      int n = id / 96, e0 = (id - n * 96) * 8;
      int b = n / 224, nl = n - b * 224;
      uint4 u = {0u,0u,0u,0u};
      if (nl < 196){
        const float* sp = tr + ((size_t)(b * 196 + nl)) * 768 + e0;
        u.x = pk2(sp[0], sp[1]); u.y = pk2(sp[2], sp[3]);
        u.z = pk2(sp[4], sp[5]); u.w = pk2(sp[6], sp[7]);
      }
      *(uint4*)(transb + (size_t)n * 768 + e0) = u;
    }
  } else {                                          // ---- scales ----
    int i = (B - 5728) * 256 + t;
    if (i < 512){
      float sc1 = g1[i] / sqrtf(v1[i] + 1e-3f);
      s1[i] = sc1; o1[i] = (mcb[i] - m1[i]) * sc1 + b1[i];
      float sc2 = g2[i] / sqrtf(v2[i] + 1e-3f);
      s2[i] = sc2; o2[i] = (rcb[i] - m2[i]) * sc2 + b2[i];
    }
  }
}

// ---------- K1: patch-embed split-K GEMM, 8 splits (1 per XCD), 448 blocks ----------
__global__ void __launch_bounds__(256, 4) dra_k1(const uint16_t* __restrict__ decT,
    const uint16_t* __restrict__ wpe2, float* __restrict__ part)
{
  __shared__ uint16_t lA[128 * 32];
  __shared__ uint16_t lB[128 * 32];
  int t = threadIdx.x;
  int L = blockIdx.x;
  int s = L & 7, n = L >> 3;           // split s pinned to xcd s; n in [0,56)
  int tok_t = n >> 2, co_t = n & 3;
  int bco  = co_t * 128;
  int tok0 = tok_t * 128;
  int lane = t & 63, w = t >> 6;
  int wm = w >> 1, wn = w & 1;
  int lr = lane & 15, lg = lane >> 4;

  const uint16_t* aB[2]; const uint16_t* bB[2]; int uu[2];
  #pragma unroll
  for (int i = 0; i < 2; i++){
    int u = t + i * 256; uu[i] = u;
    int row = u >> 2, h = u & 3;
    int token = tok0 + row;
    int b = token / 224, tl = token - b * 224;
    if (tl > 195) tl = 195;                       // clamp pad tokens (finite garbage, unused later)
    int py = tl / 14, px = tl - py * 14;
    aB[i] = decT + ((size_t)b * 12544 + py * 896 + px * 8) * 512 + h * 8;
    bB[i] = wpe2 + (size_t)(bco + row) * 32768 + h * 8;
  }

  const v4f vzero = {0.f,0.f,0.f,0.f};
  v4f acc[4][4];
  #pragma unroll
  for (int i = 0; i < 4; i++)
    #pragma unroll
    for (int j = 0; j < 4; j++) acc[i][j] = vzero;

  for (int pix = s * 8; pix < s * 8 + 8; ++pix){
    int ky = pix >> 3, kx = pix & 7;
    int poff = (ky * 112 + kx) * 512;
    int k0p  = pix * 512;
    for (int ci0 = 0; ci0 < 512; ci0 += 32){
      gl16(aB[0] + poff + ci0, &lA[uu[0] * 8]);
      gl16(aB[1] + poff + ci0, &lA[uu[1] * 8]);
      gl16(bB[0] + k0p + ci0,  &lB[uu[0] * 8]);
      gl16(bB[1] + k0p + ci0,  &lB[uu[1] * 8]);
      __syncthreads();
      v8s av[4], bv[4];
      #pragma unroll
      for (int mf = 0; mf < 4; mf++) av[mf] = *(const v8s*)&lA[(wm*64 + mf*16 + lr) * 32 + lg * 8];
      #pragma unroll
      for (int nf = 0; nf < 4; nf++) bv[nf] = *(const v8s*)&lB[(wn*64 + nf*16 + lr) * 32 + lg * 8];
      #pragma unroll
      for (int mf = 0; mf < 4; mf++)
        #pragma unroll
        for (int nf = 0; nf < 4; nf++)
          acc[mf][nf] = __builtin_amdgcn_mfma_f32_16x16x32_bf16(av[mf], bv[nf], acc[mf][nf], 0, 0, 0);
      __syncthreads();
    }
  }
  float* pd = part + (size_t)s * 917504;
  #pragma unroll
  for (int mf = 0; mf < 4; mf++){
    #pragma unroll
    for (int nf = 0; nf < 4; nf++){
      int tokg = tok0 + wm*64 + mf*16 + lg*4;
      int cog  = bco  + wn*64 + nf*16 + lr;
      #pragma unroll
      for (int r = 0; r < 4; r++)
        pd[(size_t)(tokg + r) * 512 + cog] = acc[mf][nf][r];
    }
  }
}

// reduce 8 split partials + bias -> dlb bf16 [1792][512]
__global__ void __launch_bounds__(256) dra_red(const float* __restrict__ part,
    const float* __restrict__ peb, uint16_t* __restrict__ dlb){
  int id = blockIdx.x * 256 + threadIdx.x;
  if (id >= 114688) return;
  int tok = id >> 6, c8 = (id & 63) * 8;
  float a0=0,a1=0,a2=0,a3=0,a4=0,a5=0,a6=0,a7=0;
  #pragma unroll
  for (int s = 0; s < 8; s++){
    const float* p = part + (size_t)s * 917504 + (size_t)tok * 512 + c8;
    float4 x = *(const float4*)p, y = *(const float4*)(p + 4);
    a0 += x.x; a1 += x.y; a2 += x.z; a3 += x.w;
    a4 += y.x; a5 += y.y; a6 += y.z; a7 += y.w;
  }
  const float4 b0 = *(const float4*)(peb + c8), b1 = *(const float4*)(peb + c8 + 4);
  uint4 o; o.x = pk2(a0 + b0.x, a1 + b0.y); o.y = pk2(a2 + b0.z, a3 + b0.w);
  o.z = pk2(a4 + b1.x, a5 + b1.y); o.w = pk2(a6 + b1.z, a7 + b1.w);
  *(uint4*)(dlb + (size_t)tok * 512 + c8) = o;
}

// ---------- generic NT GEMM (attention chain): D[m][n] = sum_k A[m][k]*B[n][k] ----------
// BM = MREP*32, BN=64, BK=32, 256 threads (2x2 waves). Staging via global_load_lds with
// source-chunk swizzle c^((row>>1)&3): even rows cycle all 4 slots -> 2 lanes/bank (free).
template<int MREP>
__global__ void __launch_bounds__(256, 2) dra_gemm(
    const uint16_t* __restrict__ A, const uint16_t* __restrict__ Bn, void* __restrict__ Dv,
    int M, int N, int K, int lda, int ldb, int ldd,
    long long sAz, long long sBz, long long sDz,
    int epi, const float* __restrict__ svec, const float* __restrict__ ovec)
{
  constexpr int BM = MREP * 32;
  __shared__ uint16_t lA[BM * 32];
  __shared__ uint16_t lB[64 * 32];
  int t = threadIdx.x, z = blockIdx.z;
  int bm = blockIdx.x * BM, bn = blockIdx.y * 64;
  const uint16_t* Az = A + (size_t)z * sAz;
  const uint16_t* Bz = Bn + (size_t)z * sBz;
  int lane = t & 63, w = t >> 6;
  int wm = w >> 1, wn = w & 1;
  int lr = lane & 15, lg = lane >> 4;

  const uint16_t* aSrc[MREP/2]; int uuA[MREP/2];
  #pragma unroll
  for (int i = 0; i < MREP/2; i++){
    int u = t + i * 256; uuA[i] = u;
    int row = u >> 2, c = u & 3;
    int cs = c ^ ((row >> 1) & 3);
    int rg = bm + row; if (rg >= M) rg = M - 1;
    aSrc[i] = Az + (size_t)rg * lda + cs * 8;
  }
  const uint16_t* bSrc;
  {
    int row = t >> 2, c = t & 3;
    int cs = c ^ ((row >> 1) & 3);
    bSrc = Bz + (size_t)(bn + row) * ldb + cs * 8;
  }

  int aoff[MREP], boff[2];
  #pragma unroll
  for (int mf = 0; mf < MREP; mf++){
    int R = wm*(MREP*16) + mf*16 + lr;
    aoff[mf] = R * 32 + (lg ^ ((R >> 1) & 3)) * 8;
  }
  #pragma unroll
  for (int nf = 0; nf < 2; nf++){
    int R = wn*32 + nf*16 + lr;
    boff[nf] = R * 32 + (lg ^ ((R >> 1) & 3)) * 8;
  }

  const v4f vzero = {0.f, 0.f, 0.f, 0.f};
  v4f acc[MREP][2];
  #pragma unroll
  for (int i = 0; i < MREP; i++){ acc[i][0] = vzero; acc[i][1] = vzero; }

  for (int k0 = 0; k0 < K; k0 += 32){
    #pragma unroll
    for (int i = 0; i < MREP/2; i++)
      gl16(aSrc[i] + k0, &lA[uuA[i] * 8]);
    gl16(bSrc + k0, &lB[t * 8]);
    __syncthreads();
    v8s av[MREP], bv[2];
    #pragma unroll
    for (int mf = 0; mf < MREP; mf++) av[mf] = *(const v8s*)&lA[aoff[mf]];
    #pragma unroll
    for (int nf = 0; nf < 2; nf++)    bv[nf] = *(const v8s*)&lB[boff[nf]];
    #pragma unroll
    for (int mf = 0; mf < MREP; mf++)
      #pragma unroll
      for (int nf = 0; nf < 2; nf++)
        acc[mf][nf] = __builtin_amdgcn_mfma_f32_16x16x32_bf16(av[mf], bv[nf], acc[mf][nf], 0, 0, 0);
    __syncthreads();
  }

  #pragma unroll
  for (int mf = 0; mf < MREP; mf++){
    #pragma unroll
    for (int nf = 0; nf < 2; nf++){
      int mg0 = bm + wm*(MREP*16) + mf*16 + lg*4;
      int ng  = bn + wn*32 + nf*16 + lr;
      #pragma unroll
      for (int r = 0; r < 4; r++){
        int mg = mg0 + r;
        if (mg < M){
          float val = acc[mf][nf][r];
          size_t di = (size_t)z * sDz + (size_t)mg * ldd + ng;
          if (epi == 0)      ((float*)Dv)[di] = val;
          else if (epi == 1) ((uint16_t*)Dv)[di] = f2bf(val);
          else ((float*)Dv)[di] = fmaxf(val * svec[mg] + ovec[mg], 0.f);
        }
      }
    }
  }
}

// ---------- InstanceNorm stats: two-stage deterministic tree reduction ----------
__global__ void __launch_bounds__(256) dra_stats1(const float* __restrict__ sim,
                                                  double* __restrict__ ps){
  __shared__ double d1[256], d2[256];
  int b = blockIdx.y, blk = blockIdx.x, t = threadIdx.x;
  const float* s = sim + (size_t)b * 262144 + (size_t)blk * 2048 + t * 8;
  float4 x = *(const float4*)s, y = *(const float4*)(s + 4);
  double p1 = (double)x.x + x.y + x.z + x.w + y.x + y.y + y.z + y.w;
  double p2 = (double)x.x*x.x + (double)x.y*x.y + (double)x.z*x.z + (double)x.w*x.w
            + (double)y.x*y.x + (double)y.y*y.y + (double)y.z*y.z + (double)y.w*y.w;
  d1[t] = p1; d2[t] = p2;
  __syncthreads();
  for (int o = 128; o > 0; o >>= 1){
    if (t < o){ d1[t] += d1[t + o]; d2[t] += d2[t + o]; }
    __syncthreads();
  }
  if (t == 0){
    ps[(b * 128 + blk) * 2 + 0] = d1[0];
    ps[(b * 128 + blk) * 2 + 1] = d2[0];
  }
}

__global__ void __launch_bounds__(128) dra_stats2(const double* __restrict__ ps,
    const float* __restrict__ psig, const float* __restrict__ psib, float* __restrict__ ac){
  __shared__ double d1[128], d2[128];
  int b = blockIdx.x, t = threadIdx.x;
  d1[t] = ps[(b * 128 + t) * 2 + 0];
  d2[t] = ps[(b * 128 + t) * 2 + 1];
  __syncthreads();
  for (int o = 64; o > 0; o >>= 1){
    if (t < o){ d1[t] += d1[t + o]; d2[t] += d2[t + o]; }
    __syncthreads();
  }
  if (t == 0){
    double mean = d1[0] * (1.0 / 262144.0);
    double var  = d2[0] * (1.0 / 262144.0) - mean * mean;
    float a = psig[0] / (float)sqrt(var + 1e-3);
    ac[b * 2 + 0] = a;
    ac[b * 2 + 1] = psib[0] - (float)mean * a;
  }
}

// ---------- row softmax: P[b][s][t] bf16 ----------
__global__ void __launch_bounds__(256) dra_soft(const float* __restrict__ sim,
    const float* __restrict__ ac, uint16_t* __restrict__ P){
  int srow = blockIdx.x, b = blockIdx.y, t = threadIdx.x;
  const float* row = sim + (size_t)b * 262144 + (size_t)srow * 512;
  float a = ac[b * 2], c = ac[b * 2 + 1];
  float v0 = row[t] * a + c, v1 = row[t + 256] * a + c;
  __shared__ float red[256];
  red[t] = fmaxf(v0, v1);
  __syncthreads();
  for (int o = 128; o > 0; o >>= 1){
    if (t < o) red[t] = fmaxf(red[t], red[t + o]);
    __syncthreads();
  }
  float m = red[0];
  __syncthreads();
  float e0 = __expf(v0 - m), e1 = __expf(v1 - m);
  red[t] = e0 + e1;
  __syncthreads();
  for (int o = 128; o > 0; o >>= 1){
    if (t < o) red[t] += red[t + o];
    __syncthreads();
  }
  float inv = 1.f / red[0];
  uint16_t* pr = P + (size_t)b * 262144 + (size_t)srow * 512;
  pr[t] = f2bf(e0 * inv); pr[t + 256] = f2bf(e1 * inv);
}

// ---------- K3: mask conv + BN1 + ReLU, fused x recon-upsample -> out (round-5 best) ----------
__global__ void __launch_bounds__(256, 4) dra_k3(const uint16_t* __restrict__ decT,
    const uint16_t* __restrict__ mcw, const float* __restrict__ s1,
    const float* __restrict__ o1, const float* __restrict__ recon,
    float* __restrict__ outp)
{
  __shared__ uint16_t lA[128 * 32];
  __shared__ uint16_t lB[128 * 32];
  int t = threadIdx.x;
  int L = blockIdx.x;
  int x = L & 7, n = L >> 3;          // n in [0,392)
  int co_t = n & 3, pg = n >> 2;      // pg in [0,98)
  int p = pg * 8 + x;                 // pos-tile x batch, pinned to xcd x
  int bz = p / 98, pt = p - bz * 98;
  int bco  = co_t * 128;
  int pos0 = pt * 128;
  int lane = t & 63, w = t >> 6;
  int wm = w >> 1, wn = w & 1;
  int lr = lane & 15, lg = lane >> 4;

  const uint16_t* aB[2]; const uint16_t* bB[2]; int uu[2];
  #pragma unroll
  for (int i = 0; i < 2; i++){
    int u = t + i * 256; uu[i] = u;
    int row = u >> 2, h = u & 3;
    aB[i] = mcw  + (size_t)(bco + row) * 512 + h * 8;
    bB[i] = decT + ((size_t)bz * 12544 + pos0 + row) * 512 + h * 8;
  }

  const v4f vzero = {0.f,0.f,0.f,0.f};
  v4f acc[4][4];
  #pragma unroll
  for (int i = 0; i < 4; i++)
    #pragma unroll
    for (int j = 0; j < 4; j++) acc[i][j] = vzero;

  for (int k0 = 0; k0 < 512; k0 += 32){
    gl16(aB[0] + k0, &lA[uu[0] * 8]);
    gl16(aB[1] + k0, &lA[uu[1] * 8]);
    gl16(bB[0] + k0, &lB[uu[0] * 8]);
    gl16(bB[1] + k0, &lB[uu[1] * 8]);
    __syncthreads();
    v8s av[4], bv[4];
    #pragma unroll
    for (int mf = 0; mf < 4; mf++) av[mf] = *(const v8s*)&lA[(wm*64 + mf*16 + lr) * 32 + lg * 8];
    #pragma unroll
    for (int nf = 0; nf < 4; nf++) bv[nf] = *(const v8s*)&lB[(wn*64 + nf*16 + lr) * 32 + lg * 8];
    #pragma unroll
    for (int mf = 0; mf < 4; mf++)
      #pragma unroll
      for (int nf = 0; nf < 4; nf++)
        acc[mf][nf] = __builtin_amdgcn_mfma_f32_16x16x32_bf16(av[mf], bv[nf], acc[mf][nf], 0, 0, 0);
    __syncthreads();
  }

  #pragma unroll
  for (int mf = 0; mf < 4; mf++){
    #pragma unroll
    for (int r = 0; r < 4; r++){
      int co = bco + wm*64 + mf*16 + lg*4 + r;
      float sc = s1[co], of = o1[co];
      const float* rrow = recon + (size_t)co * 1792 + bz * 224;
      #pragma unroll
      for (int nf = 0; nf < 4; nf++){
        int pos = pos0 + wn*64 + nf*16 + lr;
        int h = pos / 112, wd = pos - h * 112;
        int pcol = (h >> 3) * 14 + (wd >> 3);
        float mask = fmaxf(acc[mf][nf][r] * sc + of, 0.f);
        outp[((size_t)(bz * 512 + co)) * 12544 + pos] = mask * rrow[pcol];
      }
    }
  }
}

// ---------- launch ----------
extern "C" void kernel_launch(void* const* d_in, const int* in_sizes, int n_in,
                              void* d_out, int out_size, void* d_ws, size_t ws_size,
                              hipStream_t stream) {
  (void)in_sizes; (void)n_in; (void)out_size; (void)ws_size;
  const float* dec   = (const float*)d_in[0];
  const float* trans = (const float*)d_in[1];
  const float* pe_w  = (const float*)d_in[2];
  const float* pe_b  = (const float*)d_in[3];
  const float* mc_w  = (const float*)d_in[4];
  const float* mc_b  = (const float*)d_in[5];
  const float* bn1g  = (const float*)d_in[6];
  const float* bn1b  = (const float*)d_in[7];
  const float* bn1m  = (const float*)d_in[8];
  const float* bn1v  = (const float*)d_in[9];
  const float* wq    = (const float*)d_in[10];
  const float* wk    = (const float*)d_in[11];
  const float* wv    = (const float*)d_in[12];
  const float* wo    = (const float*)d_in[13];
  const float* psig  = (const float*)d_in[14];
  const float* psib  = (const float*)d_in[15];
  const float* rc_w  = (const float*)d_in[16];
  const float* rc_b  = (const float*)d_in[17];
  const float* bn2g  = (const float*)d_in[18];
  const float* bn2b  = (const float*)d_in[19];
  const float* bn2m  = (const float*)d_in[20];
  const float* bn2v  = (const float*)d_in[21];

  char* p = (char*)d_ws;
  auto take = [&](size_t bytes) -> void* {
    void* r = (void*)p; p += (bytes + 255) & ~(size_t)255; return r;
  };
  uint16_t* decT   = (uint16_t*)take((size_t)8 * 12544 * 512 * 2);   // 102.8 MB
  uint16_t* wpe2   = (uint16_t*)take((size_t)512 * 32768 * 2);       // 33.5 MB
  uint16_t* mcw    = (uint16_t*)take((size_t)512 * 512 * 2);
  uint16_t* rcw    = (uint16_t*)take((size_t)512 * 512 * 2);
  uint16_t* wqT    = (uint16_t*)take((size_t)512 * 512 * 2);
  uint16_t* woT    = (uint16_t*)take((size_t)512 * 512 * 2);
  uint16_t* wkT    = (uint16_t*)take((size_t)512 * 768 * 2);
  uint16_t* wvT    = (uint16_t*)take((size_t)512 * 768 * 2);
  uint16_t* transb = (uint16_t*)take((size_t)1792 * 768 * 2);
  float*    s1v    = (float*)take(512 * 4);
  float*    o1v    = (float*)take(512 * 4);
  float*    s2v    = (float*)take(512 * 4);
  float*    o2v    = (float*)take(512 * 4);
  uint16_t* dlb    = (uint16_t*)take((size_t)1792 * 512 * 2);
  uint16_t* Qt     = (uint16_t*)take((size_t)512 * 1792 * 2);
  uint16_t* Kt     = (uint16_t*)take((size_t)512 * 1792 * 2);
  uint16_t* Vb     = (uint16_t*)take((size_t)1792 * 512 * 2);
  float*    ac     = (float*)take(256);
  double*   ps     = (double*)take((size_t)8 * 128 * 2 * 8);         // 16 KB stats partials
  float*    part   = (float*)take((size_t)8 * 1792 * 512 * 4);       // 29.4 MB (8 splits)
  // alias attention temps inside part (consumed by dra_red before these are written)
  float*    simb   = part;                                            // 8.39 MB
  uint16_t* P      = (uint16_t*)(part + 2097152);                     // 4.19 MB
  uint16_t* outb   = P + 2097152;                                     // 1.84 MB
  uint16_t* out2   = outb + 917504;                                   // 1.84 MB
  float*    recon  = (float*)(out2 + 917504);                         // 3.67 MB

  // fused prep (tdec 128x128 + wpe2-transpose + cvt x2 + tcvt x4 + transb + scales)
  dra_prep<<<5730, 256, 0, stream>>>(dec, decT, pe_w, wpe2, mc_w, mcw, rc_w, rcw,
      wq, wqT, wk, wkT, wv, wvT, wo, woT, trans, transb,
      mc_b, bn1g, bn1b, bn1m, bn1v, rc_b, bn2g, bn2b, bn2m, bn2v,
      s1v, o1v, s2v, o2v);

  // patch embedding: 8-way split-K partials + reduce (-> dlb bf16)
  dra_k1<<<448, 256, 0, stream>>>(decT, wpe2, part);
  dra_red<<<448, 256, 0, stream>>>(part, pe_b, dlb);

  // Qt[s][n] ; Kt[t][n] ; Vb[n][t]
  dra_gemm<2><<<dim3(8, 28, 1), 256, 0, stream>>>(wqT, dlb, Qt, 512, 1792, 512,
      512, 512, 1792, 0, 0, 0, 1, nullptr, nullptr);
  dra_gemm<2><<<dim3(8, 28, 1), 256, 0, stream>>>(wkT, transb, Kt, 512, 1792, 768,
      768, 768, 1792, 0, 0, 0, 1, nullptr, nullptr);
  dra_gemm<2><<<dim3(28, 8, 1), 256, 0, stream>>>(transb, wvT, Vb, 1792, 512, 768,
      768, 768, 512, 0, 0, 0, 1, nullptr, nullptr);

  // sim = Qt x Kt over padded tokens (zeros in pad cols of Kt)
  dra_gemm<2><<<dim3(8, 8, 8), 256, 0, stream>>>(Qt, Kt, simb, 512, 512, 224,
      1792, 1792, 512, 224, 224, 262144, 0, nullptr, nullptr);
  dra_stats1<<<dim3(128, 8), 256, 0, stream>>>(simb, ps);
  dra_stats2<<<8, 128, 0, stream>>>(ps, psig, psib, ac);
  dra_soft<<<dim3(512, 8), 256, 0, stream>>>(simb, ac, P);

  // out = P x V ; out2 = out x wo ; recon = relu(bn2(rc(out2)))
  dra_gemm<2><<<dim3(4, 8, 8), 256, 0, stream>>>(Vb, P, outb, 224, 512, 512,
      512, 512, 512, 114688, 262144, 114688, 1, nullptr, nullptr);
  dra_gemm<2><<<dim3(28, 8, 1), 256, 0, stream>>>(outb, woT, out2, 1792, 512, 512,
      512, 512, 512, 0, 0, 0, 1, nullptr, nullptr);
  dra_gemm<2><<<dim3(8, 28, 1), 256, 0, stream>>>(rcw, out2, recon, 512, 1792, 512,
      512, 512, 1792, 0, 0, 0, 2, s2v, o2v);

  // mask conv + BN1 + ReLU, x upsampled recon -> final output
  dra_k3<<<3136, 256, 0, stream>>>(decT, mcw, s1v, o1v, recon, (float*)d_out);
}

// Round 18
// 382.970 us; speedup vs baseline: 1.0481x; 1.0052x over previous
//
#include <hip/hip_runtime.h>
#include <stdint.h>

// ---------- types & helpers ----------
typedef __attribute__((ext_vector_type(8))) short v8s;   // 8 x bf16 (4 VGPRs)
typedef __attribute__((ext_vector_type(4))) float v4f;   // MFMA C/D frag

__device__ __forceinline__ uint16_t f2bf(float x){
  uint32_t u = __float_as_uint(x);
  return (uint16_t)((u + 0x7FFFu + ((u >> 16) & 1u)) >> 16);  // RNE
}
__device__ __forceinline__ uint32_t pk2(float a, float b){
  return (uint32_t)f2bf(a) | ((uint32_t)f2bf(b) << 16);
}

// async global->LDS, 16B per lane. LDS dest is wave-uniform-base + lane*16 (linear).
__device__ __forceinline__ void gl16(const uint16_t* g, uint16_t* l){
  __builtin_amdgcn_global_load_lds((const __attribute__((address_space(1))) void*)g,
                                   (__attribute__((address_space(3))) void*)l, 16, 0, 0);
}

// ---------- fused prep: one launch, block-range dispatch ----------
// [0,3136)      tdec : dec f32 NCHW -> decT bf16 [b][pos][ci] (128x128 tile, rot-swizzle)
// [3136,4160)   wpe2 : pe_w -> [co][pix*512+ci] bf16 via LDS transpose (contiguous reads)
// [4160,4288)   cvt mcw ; [4288,4416) cvt rcw
// [4416,4544)   tcvt wq ; [4544,4736) tcvt wk ; [4736,4928) tcvt wv ; [4928,5056) tcvt wo
// [5056,5728)   transb  ; [5728,5730) scales
__device__ __forceinline__ void prep_cvt(const float* s, uint16_t* d, int id, int n8){
  if (id >= n8) return;
  const float4* sp = (const float4*)(s + (size_t)id * 8);
  float4 f0 = sp[0], f1 = sp[1];
  uint4 u; u.x = pk2(f0.x, f0.y); u.y = pk2(f0.z, f0.w);
  u.z = pk2(f1.x, f1.y); u.w = pk2(f1.z, f1.w);
  *(uint4*)(d + (size_t)id * 8) = u;
}
__device__ __forceinline__ void prep_tcvt(const float* s, uint16_t* d, int id, int R, int C){
  int r8 = R >> 3;
  if (id >= C * r8) return;
  int c = id / r8, r0 = (id - c * r8) * 8;
  float v[8];
  #pragma unroll
  for (int e = 0; e < 8; e++) v[e] = s[(size_t)(r0 + e) * C + c];
  uint4 u; u.x = pk2(v[0], v[1]); u.y = pk2(v[2], v[3]);
  u.z = pk2(v[4], v[5]); u.w = pk2(v[6], v[7]);
  *(uint4*)(d + (size_t)c * R + r0) = u;
}

__global__ void __launch_bounds__(256) dra_prep(
    const float* __restrict__ dec, uint16_t* __restrict__ decT,
    const float* __restrict__ pw, uint16_t* __restrict__ w2,
    const float* __restrict__ mc_w, uint16_t* __restrict__ mcw,
    const float* __restrict__ rc_w, uint16_t* __restrict__ rcw,
    const float* __restrict__ wq, uint16_t* __restrict__ wqT,
    const float* __restrict__ wk, uint16_t* __restrict__ wkT,
    const float* __restrict__ wv, uint16_t* __restrict__ wvT,
    const float* __restrict__ wo, uint16_t* __restrict__ woT,
    const float* __restrict__ tr, uint16_t* __restrict__ transb,
    const float* __restrict__ mcb, const float* __restrict__ g1, const float* __restrict__ b1,
    const float* __restrict__ m1, const float* __restrict__ v1,
    const float* __restrict__ rcb, const float* __restrict__ g2, const float* __restrict__ b2,
    const float* __restrict__ m2, const float* __restrict__ v2,
    float* __restrict__ s1, float* __restrict__ o1, float* __restrict__ s2, float* __restrict__ o2)
{
  __shared__ uint16_t lt[128 * 128];   // 32KB; tdec: [128 pos][128 ci]; wpe2: [64 pix][256 cl]
  int B = blockIdx.x, t = threadIdx.x;

  if (B < 3136){                                    // ---- tdec (128 pos x 128 ci tile) ----
    int pos0 = (B % 98) * 128;
    int ci0  = ((B / 98) & 3) * 128;
    int b    = B / 392;
    // write: element (p,c) -> lt[p*128 + (((c>>3)+(p>>2))&15)*8 + (c&7)]
    #pragma unroll
    for (int i = 0; i < 16; i++){
      int u = t + i * 256;
      int ci_l = u >> 5, p4 = (u & 31) * 4;
      const float4 f = *(const float4*)(dec + ((size_t)(b * 512 + ci0 + ci_l)) * 12544 + pos0 + p4);
      float v[4] = {f.x, f.y, f.z, f.w};
      #pragma unroll
      for (int j = 0; j < 4; j++){
        int p = p4 + j;
        int bp = ((ci_l >> 3) + (p >> 2)) & 15;
        lt[p * 128 + bp * 8 + (ci_l & 7)] = f2bf(v[j]);
      }
    }
    __syncthreads();
    #pragma unroll
    for (int i = 0; i < 8; i++){
      int idx = t + i * 256;
      int p_l = idx >> 4, u = idx & 15;
      int bp = (u + (p_l >> 2)) & 15;
      uint4 v = *(const uint4*)&lt[p_l * 128 + bp * 8];
      *(uint4*)(decT + ((size_t)b * 12544 + pos0 + p_l) * 512 + ci0 + u * 8) = v;
    }
  } else if (B < 4160){                             // ---- wpe2 via LDS transpose ----
    int blk = B - 3136;                             // co*2 + cihalf
    int co = blk >> 1, ch = blk & 1;
    const float* src = pw + (size_t)co * 32768 + ch * 16384;   // 64KB contiguous
    #pragma unroll
    for (int i = 0; i < 16; i++){
      int id4 = (t + i * 256) * 4;
      const float4 f = *(const float4*)(src + id4);
      int cl = id4 >> 6, pix0 = id4 & 63;
      float v[4] = {f.x, f.y, f.z, f.w};
      #pragma unroll
      for (int j = 0; j < 4; j++){
        int pix = pix0 + j;
        int bp = ((cl >> 3) + pix) & 31;
        lt[pix * 256 + bp * 8 + (cl & 7)] = f2bf(v[j]);
      }
    }
    __syncthreads();
    #pragma unroll
    for (int i = 0; i < 8; i++){
      int unit = t + i * 256;
      int pix = unit >> 5, u = unit & 31;
      int bp = (u + pix) & 31;
      uint4 v = *(const uint4*)&lt[pix * 256 + bp * 8];
      *(uint4*)(w2 + (size_t)co * 32768 + pix * 512 + ch * 256 + u * 8) = v;
    }
  } else if (B < 4288){ prep_cvt(mc_w, mcw, (B - 4160) * 256 + t, 32768); }
  else if (B < 4416){ prep_cvt(rc_w, rcw, (B - 4288) * 256 + t, 32768); }
  else if (B < 4544){ prep_tcvt(wq, wqT, (B - 4416) * 256 + t, 512, 512); }
  else if (B < 4736){ prep_tcvt(wk, wkT, (B - 4544) * 256 + t, 768, 512); }
  else if (B < 4928){ prep_tcvt(wv, wvT, (B - 4736) * 256 + t, 768, 512); }
  else if (B < 5056){ prep_tcvt(wo, woT, (B - 4928) * 256 + t, 512, 512); }
  else if (B < 5728){                               // ---- transb ----
    int id = (B - 5056) * 256 + t;
    if (id < 1792 * 96){
      int n = id / 96, e0 = (id - n * 96) * 8;
      int b = n / 224, nl = n - b * 224;
      uint4 u = {0u,0u,0u,0u};
      if (nl < 196){
        const float* sp = tr + ((size_t)(b * 196 + nl)) * 768 + e0;
        u.x = pk2(sp[0], sp[1]); u.y = pk2(sp[2], sp[3]);
        u.z = pk2(sp[4], sp[5]); u.w = pk2(sp[6], sp[7]);
      }
      *(uint4*)(transb + (size_t)n * 768 + e0) = u;
    }
  } else {                                          // ---- scales ----
    int i = (B - 5728) * 256 + t;
    if (i < 512){
      float sc1 = g1[i] / sqrtf(v1[i] + 1e-3f);
      s1[i] = sc1; o1[i] = (mcb[i] - m1[i]) * sc1 + b1[i];
      float sc2 = g2[i] / sqrtf(v2[i] + 1e-3f);
      s2[i] = sc2; o2[i] = (rcb[i] - m2[i]) * sc2 + b2[i];
    }
  }
}

// ---------- K1: patch-embed split-K GEMM, 16 splits, 896 blocks (R16 known-good) ----------
__global__ void __launch_bounds__(256, 4) dra_k1(const uint16_t* __restrict__ decT,
    const uint16_t* __restrict__ wpe2, float* __restrict__ part)
{
  __shared__ uint16_t lA[128 * 32];
  __shared__ uint16_t lB[128 * 32];
  int t = threadIdx.x;
  int L = blockIdx.x;
  int x = L & 7, n = L >> 3;           // n in [0,112)
  int shi = n / 56, rem = n - shi * 56;
  int tok_t = rem >> 2, co_t = rem & 3;
  int s    = shi * 8 + x;              // split 0..15 pinned to xcd x
  int bco  = co_t * 128;
  int tok0 = tok_t * 128;
  int lane = t & 63, w = t >> 6;
  int wm = w >> 1, wn = w & 1;
  int lr = lane & 15, lg = lane >> 4;

  const uint16_t* aB[2]; const uint16_t* bB[2]; int uu[2];
  #pragma unroll
  for (int i = 0; i < 2; i++){
    int u = t + i * 256; uu[i] = u;
    int row = u >> 2, h = u & 3;
    int token = tok0 + row;
    int b = token / 224, tl = token - b * 224;
    if (tl > 195) tl = 195;                       // clamp pad tokens (finite garbage, unused later)
    int py = tl / 14, px = tl - py * 14;
    aB[i] = decT + ((size_t)b * 12544 + py * 896 + px * 8) * 512 + h * 8;
    bB[i] = wpe2 + (size_t)(bco + row) * 32768 + h * 8;
  }

  const v4f vzero = {0.f,0.f,0.f,0.f};
  v4f acc[4][4];
  #pragma unroll
  for (int i = 0; i < 4; i++)
    #pragma unroll
    for (int j = 0; j < 4; j++) acc[i][j] = vzero;

  for (int pix = s * 4; pix < s * 4 + 4; ++pix){
    int ky = pix >> 3, kx = pix & 7;
    int poff = (ky * 112 + kx) * 512;
    int k0p  = pix * 512;
    for (int ci0 = 0; ci0 < 512; ci0 += 32){
      gl16(aB[0] + poff + ci0, &lA[uu[0] * 8]);
      gl16(aB[1] + poff + ci0, &lA[uu[1] * 8]);
      gl16(bB[0] + k0p + ci0,  &lB[uu[0] * 8]);
      gl16(bB[1] + k0p + ci0,  &lB[uu[1] * 8]);
      __syncthreads();
      v8s av[4], bv[4];
      #pragma unroll
      for (int mf = 0; mf < 4; mf++) av[mf] = *(const v8s*)&lA[(wm*64 + mf*16 + lr) * 32 + lg * 8];
      #pragma unroll
      for (int nf = 0; nf < 4; nf++) bv[nf] = *(const v8s*)&lB[(wn*64 + nf*16 + lr) * 32 + lg * 8];
      #pragma unroll
      for (int mf = 0; mf < 4; mf++)
        #pragma unroll
        for (int nf = 0; nf < 4; nf++)
          acc[mf][nf] = __builtin_amdgcn_mfma_f32_16x16x32_bf16(av[mf], bv[nf], acc[mf][nf], 0, 0, 0);
      __syncthreads();
    }
  }
  float* pd = part + (size_t)s * 917504;
  #pragma unroll
  for (int mf = 0; mf < 4; mf++){
    #pragma unroll
    for (int nf = 0; nf < 4; nf++){
      int tokg = tok0 + wm*64 + mf*16 + lg*4;
      int cog  = bco  + wn*64 + nf*16 + lr;
      #pragma unroll
      for (int r = 0; r < 4; r++)
        pd[(size_t)(tokg + r) * 512 + cog] = acc[mf][nf][r];
    }
  }
}

// reduce 16 split partials + bias -> dlb bf16 [1792][512]
__global__ void __launch_bounds__(256) dra_red(const float* __restrict__ part,
    const float* __restrict__ peb, uint16_t* __restrict__ dlb){
  int id = blockIdx.x * 256 + threadIdx.x;
  if (id >= 114688) return;
  int tok = id >> 6, c8 = (id & 63) * 8;
  float a0=0,a1=0,a2=0,a3=0,a4=0,a5=0,a6=0,a7=0;
  #pragma unroll
  for (int s = 0; s < 16; s++){
    const float* p = part + (size_t)s * 917504 + (size_t)tok * 512 + c8;
    float4 x = *(const float4*)p, y = *(const float4*)(p + 4);
    a0 += x.x; a1 += x.y; a2 += x.z; a3 += x.w;
    a4 += y.x; a5 += y.y; a6 += y.z; a7 += y.w;
  }
  const float4 b0 = *(const float4*)(peb + c8), b1 = *(const float4*)(peb + c8 + 4);
  uint4 o; o.x = pk2(a0 + b0.x, a1 + b0.y); o.y = pk2(a2 + b0.z, a3 + b0.w);
  o.z = pk2(a4 + b1.x, a5 + b1.y); o.w = pk2(a6 + b1.z, a7 + b1.w);
  *(uint4*)(dlb + (size_t)tok * 512 + c8) = o;
}

// ---------- generic NT GEMM (attention chain): D[m][n] = sum_k A[m][k]*B[n][k] ----------
// BM = MREP*32, BN=64, BK=32, 256 threads (2x2 waves). Staging via global_load_lds with
// source-chunk swizzle c^((row>>1)&3): even rows cycle all 4 slots -> 2 lanes/bank (free).
template<int MREP>
__global__ void __launch_bounds__(256, 2) dra_gemm(
    const uint16_t* __restrict__ A, const uint16_t* __restrict__ Bn, void* __restrict__ Dv,
    int M, int N, int K, int lda, int ldb, int ldd,
    long long sAz, long long sBz, long long sDz,
    int epi, const float* __restrict__ svec, const float* __restrict__ ovec)
{
  constexpr int BM = MREP * 32;
  __shared__ uint16_t lA[BM * 32];
  __shared__ uint16_t lB[64 * 32];
  int t = threadIdx.x, z = blockIdx.z;
  int bm = blockIdx.x * BM, bn = blockIdx.y * 64;
  const uint16_t* Az = A + (size_t)z * sAz;
  const uint16_t* Bz = Bn + (size_t)z * sBz;
  int lane = t & 63, w = t >> 6;
  int wm = w >> 1, wn = w & 1;
  int lr = lane & 15, lg = lane >> 4;

  const uint16_t* aSrc[MREP/2]; int uuA[MREP/2];
  #pragma unroll
  for (int i = 0; i < MREP/2; i++){
    int u = t + i * 256; uuA[i] = u;
    int row = u >> 2, c = u & 3;
    int cs = c ^ ((row >> 1) & 3);
    int rg = bm + row; if (rg >= M) rg = M - 1;
    aSrc[i] = Az + (size_t)rg * lda + cs * 8;
  }
  const uint16_t* bSrc;
  {
    int row = t >> 2, c = t & 3;
    int cs = c ^ ((row >> 1) & 3);
    bSrc = Bz + (size_t)(bn + row) * ldb + cs * 8;
  }

  int aoff[MREP], boff[2];
  #pragma unroll
  for (int mf = 0; mf < MREP; mf++){
    int R = wm*(MREP*16) + mf*16 + lr;
    aoff[mf] = R * 32 + (lg ^ ((R >> 1) & 3)) * 8;
  }
  #pragma unroll
  for (int nf = 0; nf < 2; nf++){
    int R = wn*32 + nf*16 + lr;
    boff[nf] = R * 32 + (lg ^ ((R >> 1) & 3)) * 8;
  }

  const v4f vzero = {0.f, 0.f, 0.f, 0.f};
  v4f acc[MREP][2];
  #pragma unroll
  for (int i = 0; i < MREP; i++){ acc[i][0] = vzero; acc[i][1] = vzero; }

  for (int k0 = 0; k0 < K; k0 += 32){
    #pragma unroll
    for (int i = 0; i < MREP/2; i++)
      gl16(aSrc[i] + k0, &lA[uuA[i] * 8]);
    gl16(bSrc + k0, &lB[t * 8]);
    __syncthreads();
    v8s av[MREP], bv[2];
    #pragma unroll
    for (int mf = 0; mf < MREP; mf++) av[mf] = *(const v8s*)&lA[aoff[mf]];
    #pragma unroll
    for (int nf = 0; nf < 2; nf++)    bv[nf] = *(const v8s*)&lB[boff[nf]];
    #pragma unroll
    for (int mf = 0; mf < MREP; mf++)
      #pragma unroll
      for (int nf = 0; nf < 2; nf++)
        acc[mf][nf] = __builtin_amdgcn_mfma_f32_16x16x32_bf16(av[mf], bv[nf], acc[mf][nf], 0, 0, 0);
    __syncthreads();
  }

  #pragma unroll
  for (int mf = 0; mf < MREP; mf++){
    #pragma unroll
    for (int nf = 0; nf < 2; nf++){
      int mg0 = bm + wm*(MREP*16) + mf*16 + lg*4;
      int ng  = bn + wn*32 + nf*16 + lr;
      #pragma unroll
      for (int r = 0; r < 4; r++){
        int mg = mg0 + r;
        if (mg < M){
          float val = acc[mf][nf][r];
          size_t di = (size_t)z * sDz + (size_t)mg * ldd + ng;
          if (epi == 0)      ((float*)Dv)[di] = val;
          else if (epi == 1) ((uint16_t*)Dv)[di] = f2bf(val);
          else ((float*)Dv)[di] = fmaxf(val * svec[mg] + ovec[mg], 0.f);
        }
      }
    }
  }
}

// ---------- InstanceNorm stats: two-stage deterministic tree reduction ----------
__global__ void __launch_bounds__(256) dra_stats1(const float* __restrict__ sim,
                                                  double* __restrict__ ps){
  __shared__ double d1[256], d2[256];
  int b = blockIdx.y, blk = blockIdx.x, t = threadIdx.x;
  const float* s = sim + (size_t)b * 262144 + (size_t)blk * 2048 + t * 8;
  float4 x = *(const float4*)s, y = *(const float4*)(s + 4);
  double p1 = (double)x.x + x.y + x.z + x.w + y.x + y.y + y.z + y.w;
  double p2 = (double)x.x*x.x + (double)x.y*x.y + (double)x.z*x.z + (double)x.w*x.w
            + (double)y.x*y.x + (double)y.y*y.y + (double)y.z*y.z + (double)y.w*y.w;
  d1[t] = p1; d2[t] = p2;
  __syncthreads();
  for (int o = 128; o > 0; o >>= 1){
    if (t < o){ d1[t] += d1[t + o]; d2[t] += d2[t + o]; }
    __syncthreads();
  }
  if (t == 0){
    ps[(b * 128 + blk) * 2 + 0] = d1[0];
    ps[(b * 128 + blk) * 2 + 1] = d2[0];
  }
}

__global__ void __launch_bounds__(128) dra_stats2(const double* __restrict__ ps,
    const float* __restrict__ psig, const float* __restrict__ psib, float* __restrict__ ac){
  __shared__ double d1[128], d2[128];
  int b = blockIdx.x, t = threadIdx.x;
  d1[t] = ps[(b * 128 + t) * 2 + 0];
  d2[t] = ps[(b * 128 + t) * 2 + 1];
  __syncthreads();
  for (int o = 64; o > 0; o >>= 1){
    if (t < o){ d1[t] += d1[t + o]; d2[t] += d2[t + o]; }
    __syncthreads();
  }
  if (t == 0){
    double mean = d1[0] * (1.0 / 262144.0);
    double var  = d2[0] * (1.0 / 262144.0) - mean * mean;
    float a = psig[0] / (float)sqrt(var + 1e-3);
    ac[b * 2 + 0] = a;
    ac[b * 2 + 1] = psib[0] - (float)mean * a;
  }
}

// ---------- row softmax: P[b][s][t] bf16 ----------
__global__ void __launch_bounds__(256) dra_soft(const float* __restrict__ sim,
    const float* __restrict__ ac, uint16_t* __restrict__ P){
  int srow = blockIdx.x, b = blockIdx.y, t = threadIdx.x;
  const float* row = sim + (size_t)b * 262144 + (size_t)srow * 512;
  float a = ac[b * 2], c = ac[b * 2 + 1];
  float v0 = row[t] * a + c, v1 = row[t + 256] * a + c;
  __shared__ float red[256];
  red[t] = fmaxf(v0, v1);
  __syncthreads();
  for (int o = 128; o > 0; o >>= 1){
    if (t < o) red[t] = fmaxf(red[t], red[t + o]);
    __syncthreads();
  }
  float m = red[0];
  __syncthreads();
  float e0 = __expf(v0 - m), e1 = __expf(v1 - m);
  red[t] = e0 + e1;
  __syncthreads();
  for (int o = 128; o > 0; o >>= 1){
    if (t < o) red[t] += red[t + o];
    __syncthreads();
  }
  float inv = 1.f / red[0];
  uint16_t* pr = P + (size_t)b * 262144 + (size_t)srow * 512;
  pr[t] = f2bf(e0 * inv); pr[t + 256] = f2bf(e1 * inv);
}

// ---------- K3: mask conv + BN1 + ReLU, fused x recon-upsample -> out (round-5 best) ----------
__global__ void __launch_bounds__(256, 4) dra_k3(const uint16_t* __restrict__ decT,
    const uint16_t* __restrict__ mcw, const float* __restrict__ s1,
    const float* __restrict__ o1, const float* __restrict__ recon,
    float* __restrict__ outp)
{
  __shared__ uint16_t lA[128 * 32];
  __shared__ uint16_t lB[128 * 32];
  int t = threadIdx.x;
  int L = blockIdx.x;
  int x = L & 7, n = L >> 3;          // n in [0,392)
  int co_t = n & 3, pg = n >> 2;      // pg in [0,98)
  int p = pg * 8 + x;                 // pos-tile x batch, pinned to xcd x
  int bz = p / 98, pt = p - bz * 98;
  int bco  = co_t * 128;
  int pos0 = pt * 128;
  int lane = t & 63, w = t >> 6;
  int wm = w >> 1, wn = w & 1;
  int lr = lane & 15, lg = lane >> 4;

  const uint16_t* aB[2]; const uint16_t* bB[2]; int uu[2];
  #pragma unroll
  for (int i = 0; i < 2; i++){
    int u = t + i * 256; uu[i] = u;
    int row = u >> 2, h = u & 3;
    aB[i] = mcw  + (size_t)(bco + row) * 512 + h * 8;
    bB[i] = decT + ((size_t)bz * 12544 + pos0 + row) * 512 + h * 8;
  }

  const v4f vzero = {0.f,0.f,0.f,0.f};
  v4f acc[4][4];
  #pragma unroll
  for (int i = 0; i < 4; i++)
    #pragma unroll
    for (int j = 0; j < 4; j++) acc[i][j] = vzero;

  for (int k0 = 0; k0 < 512; k0 += 32){
    gl16(aB[0] + k0, &lA[uu[0] * 8]);
    gl16(aB[1] + k0, &lA[uu[1] * 8]);
    gl16(bB[0] + k0, &lB[uu[0] * 8]);
    gl16(bB[1] + k0, &lB[uu[1] * 8]);
    __syncthreads();
    v8s av[4], bv[4];
    #pragma unroll
    for (int mf = 0; mf < 4; mf++) av[mf] = *(const v8s*)&lA[(wm*64 + mf*16 + lr) * 32 + lg * 8];
    #pragma unroll
    for (int nf = 0; nf < 4; nf++) bv[nf] = *(const v8s*)&lB[(wn*64 + nf*16 + lr) * 32 + lg * 8];
    #pragma unroll
    for (int mf = 0; mf < 4; mf++)
      #pragma unroll
      for (int nf = 0; nf < 4; nf++)
        acc[mf][nf] = __builtin_amdgcn_mfma_f32_16x16x32_bf16(av[mf], bv[nf], acc[mf][nf], 0, 0, 0);
    __syncthreads();
  }

  #pragma unroll
  for (int mf = 0; mf < 4; mf++){
    #pragma unroll
    for (int r = 0; r < 4; r++){
      int co = bco + wm*64 + mf*16 + lg*4 + r;
      float sc = s1[co], of = o1[co];
      const float* rrow = recon + (size_t)co * 1792 + bz * 224;
      #pragma unroll
      for (int nf = 0; nf < 4; nf++){
        int pos = pos0 + wn*64 + nf*16 + lr;
        int h = pos / 112, wd = pos - h * 112;
        int pcol = (h >> 3) * 14 + (wd >> 3);
        float mask = fmaxf(acc[mf][nf][r] * sc + of, 0.f);
        outp[((size_t)(bz * 512 + co)) * 12544 + pos] = mask * rrow[pcol];
      }
    }
  }
}

// ---------- launch ----------
extern "C" void kernel_launch(void* const* d_in, const int* in_sizes, int n_in,
                              void* d_out, int out_size, void* d_ws, size_t ws_size,
                              hipStream_t stream) {
  (void)in_sizes; (void)n_in; (void)out_size; (void)ws_size;
  const float* dec   = (const float*)d_in[0];
  const float* trans = (const float*)d_in[1];
  const float* pe_w  = (const float*)d_in[2];
  const float* pe_b  = (const float*)d_in[3];
  const float* mc_w  = (const float*)d_in[4];
  const float* mc_b  = (const float*)d_in[5];
  const float* bn1g  = (const float*)d_in[6];
  const float* bn1b  = (const float*)d_in[7];
  const float* bn1m  = (const float*)d_in[8];
  const float* bn1v  = (const float*)d_in[9];
  const float* wq    = (const float*)d_in[10];
  const float* wk    = (const float*)d_in[11];
  const float* wv    = (const float*)d_in[12];
  const float* wo    = (const float*)d_in[13];
  const float* psig  = (const float*)d_in[14];
  const float* psib  = (const float*)d_in[15];
  const float* rc_w  = (const float*)d_in[16];
  const float* rc_b  = (const float*)d_in[17];
  const float* bn2g  = (const float*)d_in[18];
  const float* bn2b  = (const float*)d_in[19];
  const float* bn2m  = (const float*)d_in[20];
  const float* bn2v  = (const float*)d_in[21];

  char* p = (char*)d_ws;
  auto take = [&](size_t bytes) -> void* {
    void* r = (void*)p; p += (bytes + 255) & ~(size_t)255; return r;
  };
  uint16_t* decT   = (uint16_t*)take((size_t)8 * 12544 * 512 * 2);   // 102.8 MB
  uint16_t* wpe2   = (uint16_t*)take((size_t)512 * 32768 * 2);       // 33.5 MB
  uint16_t* mcw    = (uint16_t*)take((size_t)512 * 512 * 2);
  uint16_t* rcw    = (uint16_t*)take((size_t)512 * 512 * 2);
  uint16_t* wqT    = (uint16_t*)take((size_t)512 * 512 * 2);
  uint16_t* woT    = (uint16_t*)take((size_t)512 * 512 * 2);
  uint16_t* wkT    = (uint16_t*)take((size_t)512 * 768 * 2);
  uint16_t* wvT    = (uint16_t*)take((size_t)512 * 768 * 2);
  uint16_t* transb = (uint16_t*)take((size_t)1792 * 768 * 2);
  float*    s1v    = (float*)take(512 * 4);
  float*    o1v    = (float*)take(512 * 4);
  float*    s2v    = (float*)take(512 * 4);
  float*    o2v    = (float*)take(512 * 4);
  uint16_t* dlb    = (uint16_t*)take((size_t)1792 * 512 * 2);
  uint16_t* Qt     = (uint16_t*)take((size_t)512 * 1792 * 2);
  uint16_t* Kt     = (uint16_t*)take((size_t)512 * 1792 * 2);
  uint16_t* Vb     = (uint16_t*)take((size_t)1792 * 512 * 2);
  float*    ac     = (float*)take(256);
  double*   ps     = (double*)take((size_t)8 * 128 * 2 * 8);         // 16 KB stats partials
  float*    part   = (float*)take((size_t)16 * 1792 * 512 * 4);      // 58.7 MB (16 splits)
  // alias attention temps inside part (consumed by dra_red before these are written)
  float*    simb   = part;                                            // 8.39 MB
  uint16_t* P      = (uint16_t*)(part + 2097152);                     // 4.19 MB
  uint16_t* outb   = P + 2097152;                                     // 1.84 MB
  uint16_t* out2   = outb + 917504;                                   // 1.84 MB
  float*    recon  = (float*)(out2 + 917504);                         // 3.67 MB

  // fused prep (tdec 128x128 + wpe2-transpose + cvt x2 + tcvt x4 + transb + scales)
  dra_prep<<<5730, 256, 0, stream>>>(dec, decT, pe_w, wpe2, mc_w, mcw, rc_w, rcw,
      wq, wqT, wk, wkT, wv, wvT, wo, woT, trans, transb,
      mc_b, bn1g, bn1b, bn1m, bn1v, rc_b, bn2g, bn2b, bn2m, bn2v,
      s1v, o1v, s2v, o2v);

  // patch embedding: 16-way split-K partials + reduce (-> dlb bf16)
  dra_k1<<<896, 256, 0, stream>>>(decT, wpe2, part);
  dra_red<<<448, 256, 0, stream>>>(part, pe_b, dlb);

  // Qt[s][n] ; Kt[t][n] ; Vb[n][t]
  dra_gemm<2><<<dim3(8, 28, 1), 256, 0, stream>>>(wqT, dlb, Qt, 512, 1792, 512,
      512, 512, 1792, 0, 0, 0, 1, nullptr, nullptr);
  dra_gemm<2><<<dim3(8, 28, 1), 256, 0, stream>>>(wkT, transb, Kt, 512, 1792, 768,
      768, 768, 1792, 0, 0, 0, 1, nullptr, nullptr);
  dra_gemm<2><<<dim3(28, 8, 1), 256, 0, stream>>>(transb, wvT, Vb, 1792, 512, 768,
      768, 768, 512, 0, 0, 0, 1, nullptr, nullptr);

  // sim = Qt x Kt over padded tokens (zeros in pad cols of Kt)
  dra_gemm<2><<<dim3(8, 8, 8), 256, 0, stream>>>(Qt, Kt, simb, 512, 512, 224,
      1792, 1792, 512, 224, 224, 262144, 0, nullptr, nullptr);
  dra_stats1<<<dim3(128, 8), 256, 0, stream>>>(simb, ps);
  dra_stats2<<<8, 128, 0, stream>>>(ps, psig, psib, ac);
  dra_soft<<<dim3(512, 8), 256, 0, stream>>>(simb, ac, P);

  // out = P x V ; out2 = out x wo ; recon = relu(bn2(rc(out2)))
  dra_gemm<2><<<dim3(4, 8, 8), 256, 0, stream>>>(Vb, P, outb, 224, 512, 512,
      512, 512, 512, 114688, 262144, 114688, 1, nullptr, nullptr);
  dra_gemm<2><<<dim3(28, 8, 1), 256, 0, stream>>>(outb, woT, out2, 1792, 512, 512,
      512, 512, 512, 0, 0, 0, 1, nullptr, nullptr);
  dra_gemm<2><<<dim3(8, 28, 1), 256, 0, stream>>>(rcw, out2, recon, 512, 1792, 512,
      512, 512, 1792, 0, 0, 0, 2, s2v, o2v);

  // mask conv + BN1 + ReLU, x upsampled recon -> final output
  dra_k3<<<3136, 256, 0, stream>>>(decT, mcw, s1v, o1v, recon, (float*)d_out);
}